// Round 6
// baseline (298.857 us; speedup 1.0000x reference)
//
#include <hip/hip_runtime.h>

#define N_NODES 100000
#define N_EDGES 640000
#define N_LABEL 100000
#define CAP 64   // max stored neighbors/node; degrees ~Poisson(6.4), max ~25 -> 2.4x headroom
// IN_C=128, HID_C=128, OUT_C=64

typedef __bf16 bf16x8 __attribute__((ext_vector_type(8)));
typedef float f32x4 __attribute__((ext_vector_type(4)));

// canonical bf16 weight offsets (in shorts) inside ws weight region
#define CW1L 0
#define CB1  16384
#define CW1R 16512
#define CW2L 32896
#define CB2  41088
#define CW2R 41152
#define NWTS 49344

// fused prep kernel block ranges
#define NB_W 193                    // convw: ceil(49344/256)
#define NB_X 12500                  // convx: ceil(3200000/256)
#define NB_F 2500                   // fill:  ceil(640000/256)

__device__ __forceinline__ float bf2f(unsigned short u) {
    union { unsigned int i; float f; } c; c.i = ((unsigned int)u) << 16; return c.f;
}
__device__ __forceinline__ unsigned short f2bf(float f) {
    union { float f; unsigned int i; } c; c.f = f;
    unsigned int lsb = (c.i >> 16) & 1u;
    c.i += 0x7fffu + lsb;              // round-to-nearest-even
    return (unsigned short)(c.i >> 16);
}

// ---- dtype detection: flags[0]=1 if x is f32 storage; flags[1]=1 if edges are int64 ----
__global__ void k_detect(const unsigned int* __restrict__ xw,
                         const unsigned int* __restrict__ eiw,
                         int* __restrict__ flags) {
    int l = threadIdx.x;
    unsigned int w = xw[l];
    unsigned short lo = (unsigned short)(w & 0xffffu);
    int e = (lo >> 7) & 0xff;
    bool bf_like = (lo == 0) || (e >= 98 && e <= 138);
    unsigned long long m = __ballot(bf_like);
    unsigned int ew = eiw[2 * l + 1];
    unsigned long long mz = __ballot(ew == 0u);
    if (l == 0) {
        flags[0] = (__popcll(m) < 48) ? 1 : 0;
        flags[1] = (__popcll(mz) == 64) ? 1 : 0;
    }
}

// ---- fused prep: convw (weights->bf16) | convx (x->bf16) | fill (adjacency) ----
__global__ void k_prep(const void* W1l, const void* b1, const void* W1r,
                       const void* W2l, const void* b2, const void* W2r,
                       unsigned short* __restrict__ wts,
                       const void* __restrict__ x, unsigned short* __restrict__ xb,
                       const int* __restrict__ ei, int* __restrict__ cnt,
                       int* __restrict__ csr, const int* __restrict__ flags) {
    int b = blockIdx.x;
    int f32m = flags[0];
    if (b < NB_W) {
        int i = b * 256 + threadIdx.x;
        if (i >= NWTS) return;
        const void* src; int local;
        if      (i < CB1)  { src = W1l; local = i; }
        else if (i < CW1R) { src = b1;  local = i - CB1; }
        else if (i < CW2L) { src = W1r; local = i - CW1R; }
        else if (i < CB2)  { src = W2l; local = i - CW2L; }
        else if (i < CW2R) { src = b2;  local = i - CB2; }
        else               { src = W2r; local = i - CW2R; }
        wts[i] = f32m ? f2bf(((const float*)src)[local]) : ((const unsigned short*)src)[local];
    } else if (b < NB_W + NB_X) {
        int i = (b - NB_W) * 256 + threadIdx.x;
        if (i >= N_NODES * 32) return;
        if (f32m) {
            float4 p = ((const float4*)x)[i];
            ushort4 o;
            o.x = f2bf(p.x); o.y = f2bf(p.y); o.z = f2bf(p.z); o.w = f2bf(p.w);
            ((ushort4*)xb)[i] = o;
        } else {
            ((ushort4*)xb)[i] = ((const ushort4*)x)[i];
        }
    } else {
        int e = (b - NB_W - NB_X) * 256 + threadIdx.x;
        if (e >= N_EDGES) return;
        int i64 = flags[1];
        int src = ei[e << i64], dst = ei[(N_EDGES + e) << i64];
        int pos = atomicAdd(&cnt[dst], 1);
        if (pos < CAP) csr[dst * CAP + pos] = src;
    }
}

// ---- layer-1 gather + mean -> bf16 mb. One wave/node; 4 edges x 16 lanes x 8ch (16B loads) ----
__global__ __launch_bounds__(256) void k_agg1(
    const int* __restrict__ cnt, const int* __restrict__ csr,
    const unsigned short* __restrict__ xb, unsigned short* __restrict__ mb) {
    int n = (int)((blockIdx.x * blockDim.x + threadIdx.x) >> 6);
    if (n >= N_NODES) return;
    int lane = threadIdx.x & 63;
    int g = lane >> 4, q = lane & 15;
    int deg = cnt[n];
    int m = deg < CAP ? deg : CAP;
    int srcl = (lane < m) ? csr[n * CAP + lane] : 0;
    float s[8];
#pragma unroll
    for (int j = 0; j < 8; ++j) s[j] = 0.f;
    for (int e0 = 0; e0 < m; e0 += 4) {
        int e = e0 + g;
        int sidx = __shfl(srcl, e);
        if (e < m) {
            uint4 w = *(const uint4*)(xb + (size_t)sidx * 128 + q * 8);
            s[0] += bf2f((unsigned short)w.x); s[1] += bf2f((unsigned short)(w.x >> 16));
            s[2] += bf2f((unsigned short)w.y); s[3] += bf2f((unsigned short)(w.y >> 16));
            s[4] += bf2f((unsigned short)w.z); s[5] += bf2f((unsigned short)(w.z >> 16));
            s[6] += bf2f((unsigned short)w.w); s[7] += bf2f((unsigned short)(w.w >> 16));
        }
    }
#pragma unroll
    for (int off = 16; off < 64; off <<= 1)
#pragma unroll
        for (int j = 0; j < 8; ++j) s[j] += __shfl_xor(s[j], off);
    if (g == 0) {
        float inv = 1.0f / (deg > 1 ? (float)deg : 1.0f);
        uint4 o;
        o.x = (unsigned int)f2bf(s[0] * inv) | ((unsigned int)f2bf(s[1] * inv) << 16);
        o.y = (unsigned int)f2bf(s[2] * inv) | ((unsigned int)f2bf(s[3] * inv) << 16);
        o.z = (unsigned int)f2bf(s[4] * inv) | ((unsigned int)f2bf(s[5] * inv) << 16);
        o.w = (unsigned int)f2bf(s[6] * inv) | ((unsigned int)f2bf(s[7] * inv) << 16);
        *(uint4*)(mb + (size_t)n * 128 + q * 8) = o;
    }
}

// ---- GEMM1: W-stationary, 2 node-tiles/wave, dbuf A. Wave = out-quarter (32ch) ----
__global__ __launch_bounds__(256) void k_gemm1(
    const unsigned short* __restrict__ mb, const unsigned short* __restrict__ xb,
    const unsigned short* __restrict__ wts, unsigned short* __restrict__ h)
{
    int w = (int)((blockIdx.x * blockDim.x + threadIdx.x) >> 6);
    int lane = threadIdx.x & 63;
    int q = w & 3;          // out-channel quarter: ch [q*32, q*32+32)
    int tg = w >> 2;        // group of 2 node-tiles
    int row = lane & 15, kq = lane >> 4;

    // resident W fragments: 2 out-tiles x 8 k-steps (K=256)
    bf16x8 Wf[16];
#pragma unroll
    for (int t = 0; t < 2; ++t)
#pragma unroll
        for (int ks = 0; ks < 8; ++ks) {
            const int k0 = ks * 32;
            const unsigned short* base = wts + (k0 < 128 ? CW1L : CW1R)
                + (size_t)(q * 32 + t * 16 + row) * 128 + (k0 & 127) + kq * 8;
            Wf[t * 8 + ks] = *reinterpret_cast<const bf16x8*>(base);
        }

    int col = lane & 15, rq = lane >> 4;
    float bias0 = bf2f(wts[CB1 + q * 32 + col]);
    float bias1 = bf2f(wts[CB1 + q * 32 + 16 + col]);

    int nt0 = tg * 2;
    bf16x8 Af[2][8];

#define LOAD_A1(tile, buf)                                                            \
    {                                                                                 \
        int n0_ = (tile) * 16;                                                        \
        if (n0_ < N_NODES) {                                                          \
            const unsigned short* rm = mb + (size_t)(n0_ + row) * 128 + kq * 8;       \
            const unsigned short* rx = xb + (size_t)(n0_ + row) * 128 + kq * 8;       \
            _Pragma("unroll")                                                         \
            for (int ks = 0; ks < 4; ++ks)                                            \
                Af[buf][ks] = *reinterpret_cast<const bf16x8*>(rm + ks * 32);         \
            _Pragma("unroll")                                                         \
            for (int ks = 0; ks < 4; ++ks)                                            \
                Af[buf][4 + ks] = *reinterpret_cast<const bf16x8*>(rx + ks * 32);     \
        }                                                                             \
    }

    LOAD_A1(nt0, 0);
#pragma unroll
    for (int i = 0; i < 2; ++i) {
        int n0 = (nt0 + i) * 16;
        if (n0 >= N_NODES) continue;
        if (i < 1) LOAD_A1(nt0 + i + 1, (i + 1) & 1);
        f32x4 acc0 = (f32x4){0.f, 0.f, 0.f, 0.f};
        f32x4 acc1 = (f32x4){0.f, 0.f, 0.f, 0.f};
#pragma unroll
        for (int ks = 0; ks < 8; ++ks) {
            acc0 = __builtin_amdgcn_mfma_f32_16x16x32_bf16(Af[i & 1][ks], Wf[ks],     acc0, 0, 0, 0);
            acc1 = __builtin_amdgcn_mfma_f32_16x16x32_bf16(Af[i & 1][ks], Wf[8 + ks], acc1, 0, 0, 0);
        }
#pragma unroll
        for (int r = 0; r < 4; ++r) {
            int n = n0 + rq * 4 + r;
            float v0 = acc0[r] + bias0; v0 = v0 > 0.f ? v0 : 0.f;
            float v1 = acc1[r] + bias1; v1 = v1 > 0.f ? v1 : 0.f;
            h[(size_t)n * 128 + q * 32 + col]      = f2bf(v0);
            h[(size_t)n * 128 + q * 32 + 16 + col] = f2bf(v1);
        }
    }
#undef LOAD_A1
}

// ---- GEMM2: W-stationary, 2 tiles/wave. Wave = out-quarter (32ch of [t_l||t_r]) ----
__global__ __launch_bounds__(256) void k_gemm2(
    const unsigned short* __restrict__ h, const unsigned short* __restrict__ wts,
    unsigned short* __restrict__ tb)
{
    int w = (int)((blockIdx.x * blockDim.x + threadIdx.x) >> 6);
    int lane = threadIdx.x & 63;
    int q = w & 3;          // out quarter: q<2 -> W2l (t_l), q>=2 -> W2r (t_r)
    int tg = w >> 2;
    int row = lane & 15, kq = lane >> 4;

    const size_t wbase = (q < 2) ? (CW2L + (size_t)(q * 32) * 128)
                                 : (CW2R + (size_t)((q - 2) * 32) * 128);
    bf16x8 Wf[8];           // 2 out-tiles x 4 k-steps (K=128)
#pragma unroll
    for (int t = 0; t < 2; ++t)
#pragma unroll
        for (int ks = 0; ks < 4; ++ks)
            Wf[t * 4 + ks] = *reinterpret_cast<const bf16x8*>(
                wts + wbase + (size_t)(t * 16 + row) * 128 + ks * 32 + kq * 8);

    int col = lane & 15, rq = lane >> 4;
    int nt0 = tg * 2;
    bf16x8 Af[2][4];

#define LOAD_A2(tile, buf)                                                            \
    {                                                                                 \
        int n0_ = (tile) * 16;                                                        \
        if (n0_ < N_NODES) {                                                          \
            const unsigned short* rh = h + (size_t)(n0_ + row) * 128 + kq * 8;        \
            _Pragma("unroll")                                                         \
            for (int ks = 0; ks < 4; ++ks)                                            \
                Af[buf][ks] = *reinterpret_cast<const bf16x8*>(rh + ks * 32);         \
        }                                                                             \
    }

    LOAD_A2(nt0, 0);
#pragma unroll
    for (int i = 0; i < 2; ++i) {
        int n0 = (nt0 + i) * 16;
        if (n0 >= N_NODES) continue;
        if (i < 1) LOAD_A2(nt0 + i + 1, (i + 1) & 1);
        f32x4 acc0 = (f32x4){0.f, 0.f, 0.f, 0.f};
        f32x4 acc1 = (f32x4){0.f, 0.f, 0.f, 0.f};
#pragma unroll
        for (int ks = 0; ks < 4; ++ks) {
            acc0 = __builtin_amdgcn_mfma_f32_16x16x32_bf16(Af[i & 1][ks], Wf[ks],     acc0, 0, 0, 0);
            acc1 = __builtin_amdgcn_mfma_f32_16x16x32_bf16(Af[i & 1][ks], Wf[4 + ks], acc1, 0, 0, 0);
        }
#pragma unroll
        for (int r = 0; r < 4; ++r) {
            int n = n0 + rq * 4 + r;
            tb[(size_t)n * 128 + q * 32 + col]      = f2bf(acc0[r]);
            tb[(size_t)n * 128 + q * 32 + 16 + col] = f2bf(acc1[r]);
        }
    }
#undef LOAD_A2
}

// ---- layer-2 gather + combine: z = agg(t_l)/deg + b2 + t_r. 8 edges x 8 lanes x 8ch ----
__global__ __launch_bounds__(256) void k_agg2c(
    const int* __restrict__ cnt, const int* __restrict__ csr,
    const unsigned short* __restrict__ tb, const unsigned short* __restrict__ wts,
    float* __restrict__ z) {
    int n = (int)((blockIdx.x * blockDim.x + threadIdx.x) >> 6);
    if (n >= N_NODES) return;
    int lane = threadIdx.x & 63;
    int g = lane >> 3, q = lane & 7;
    int deg = cnt[n];
    int m = deg < CAP ? deg : CAP;
    int srcl = (lane < m) ? csr[n * CAP + lane] : 0;
    float s[8];
#pragma unroll
    for (int j = 0; j < 8; ++j) s[j] = 0.f;
    for (int e0 = 0; e0 < m; e0 += 8) {
        int e = e0 + g;
        int sidx = __shfl(srcl, e);
        if (e < m) {
            uint4 w = *(const uint4*)(tb + (size_t)sidx * 128 + q * 8);
            s[0] += bf2f((unsigned short)w.x); s[1] += bf2f((unsigned short)(w.x >> 16));
            s[2] += bf2f((unsigned short)w.y); s[3] += bf2f((unsigned short)(w.y >> 16));
            s[4] += bf2f((unsigned short)w.z); s[5] += bf2f((unsigned short)(w.z >> 16));
            s[6] += bf2f((unsigned short)w.w); s[7] += bf2f((unsigned short)(w.w >> 16));
        }
    }
#pragma unroll
    for (int off = 8; off < 64; off <<= 1)
#pragma unroll
        for (int j = 0; j < 8; ++j) s[j] += __shfl_xor(s[j], off);
    if (g == 0) {
        float inv = 1.0f / (deg > 1 ? (float)deg : 1.0f);
        uint4 tr = *(const uint4*)(tb + (size_t)n * 128 + 64 + q * 8);
        uint4 bb = *(const uint4*)(wts + CB2 + q * 8);
        float4 z0, z1;
        z0.x = s[0] * inv + bf2f((unsigned short)bb.x)         + bf2f((unsigned short)tr.x);
        z0.y = s[1] * inv + bf2f((unsigned short)(bb.x >> 16)) + bf2f((unsigned short)(tr.x >> 16));
        z0.z = s[2] * inv + bf2f((unsigned short)bb.y)         + bf2f((unsigned short)tr.y);
        z0.w = s[3] * inv + bf2f((unsigned short)(bb.y >> 16)) + bf2f((unsigned short)(tr.y >> 16));
        z1.x = s[4] * inv + bf2f((unsigned short)bb.z)         + bf2f((unsigned short)tr.z);
        z1.y = s[5] * inv + bf2f((unsigned short)(bb.z >> 16)) + bf2f((unsigned short)(tr.z >> 16));
        z1.z = s[6] * inv + bf2f((unsigned short)bb.w)         + bf2f((unsigned short)tr.w);
        z1.w = s[7] * inv + bf2f((unsigned short)(bb.w >> 16)) + bf2f((unsigned short)(tr.w >> 16));
        *(float4*)(z + (size_t)n * 64 + q * 8)     = z0;
        *(float4*)(z + (size_t)n * 64 + q * 8 + 4) = z1;
    }
}

// ---- decode: scores[e] = dot64(z[a], z[b]); 4 edges/wave, 16 lanes x float4 ----
__global__ void k_decode(const int* __restrict__ eli, const float* __restrict__ z,
                         void* __restrict__ out, const int* __restrict__ flags) {
    long long t = (long long)blockIdx.x * blockDim.x + threadIdx.x;
    int e = (int)(t >> 4);
    if (e >= N_LABEL) return;
    int f32m = flags[0], i64 = flags[1];
    int q = threadIdx.x & 15;
    int a = eli[e << i64], b = eli[(N_LABEL + e) << i64];
    float4 pa = *(const float4*)(z + (size_t)a * 64 + q * 4);
    float4 pb = *(const float4*)(z + (size_t)b * 64 + q * 4);
    float s = pa.x * pb.x + pa.y * pb.y + pa.z * pb.z + pa.w * pb.w;
#pragma unroll
    for (int off = 1; off < 16; off <<= 1) s += __shfl_xor(s, off);
    if (q == 0) {
        if (f32m) ((float*)out)[e] = s;
        else      ((unsigned short*)out)[e] = f2bf(s);
    }
}

extern "C" void kernel_launch(void* const* d_in, const int* in_sizes, int n_in,
                              void* d_out, int out_size, void* d_ws, size_t ws_size,
                              hipStream_t stream) {
    const void* x   = d_in[0];
    const int*  ei  = (const int*)d_in[1];
    const int*  eli = (const int*)d_in[2];
    const void* W1l = d_in[3];
    const void* b1  = d_in[4];
    const void* W1r = d_in[5];
    const void* W2l = d_in[6];
    const void* b2  = d_in[7];
    const void* W2r = d_in[8];

    char* ws = (char*)d_ws;
    const size_t offFlag = 0;
    const size_t offCnt  = 1024;                       // int[100000] -> 400 KB
    const size_t offWts  = 801024;                     // bf16[NWTS]  -> ~96 KB
    const size_t offCsr  = 1u << 20;                              // int[N*CAP]   25.6 MB
    const size_t offXb   = offCsr + (size_t)N_NODES * CAP * 4;    // xb bf16[N,128] 25.6 MB
    const size_t offMb   = offXb  + (size_t)N_NODES * 128 * 2;    // mb bf16 -> tb bf16
    const size_t offHz   = offMb  + (size_t)N_NODES * 128 * 2;    // h bf16 -> z f32[N,64]
    // total = 1 MB + 4*25.6 MB = 103.4 MB (same proven footprint)

    int*            flags = (int*)(ws + offFlag);
    int*            cnt   = (int*)(ws + offCnt);
    unsigned short* wts   = (unsigned short*)(ws + offWts);
    int*            csr   = (int*)(ws + offCsr);
    unsigned short* xb    = (unsigned short*)(ws + offXb);
    unsigned short* mb    = (unsigned short*)(ws + offMb);
    unsigned short* h     = (unsigned short*)(ws + offHz);

    hipMemsetAsync(ws, 0, 1u << 20, stream);   // flags + cnt (wts rewritten anyway)

    k_detect<<<1, 64, 0, stream>>>((const unsigned int*)x, (const unsigned int*)ei, flags);

    // fused convw | convx | fill
    k_prep<<<NB_W + NB_X + NB_F, 256, 0, stream>>>(W1l, b1, W1r, W2l, b2, W2r, wts,
                                                   x, xb, ei, cnt, csr, flags);

    {
        long long thr = (long long)N_NODES * 64;
        k_agg1<<<(unsigned)((thr + 255) / 256), 256, 0, stream>>>(cnt, csr, xb, mb);
    }

    // node-tiles = 6250; groups of 2 = 3125; x4 out-quarters = 12500 waves = 3125 blocks
    const int NTG = (6250 + 1) / 2;
    k_gemm1<<<NTG, 256, 0, stream>>>(mb, xb, wts, h);

    unsigned short* tb = mb;  // mb dead after gemm1
    k_gemm2<<<NTG, 256, 0, stream>>>(h, wts, tb);

    float* z = (float*)(ws + offHz);  // h dead after gemm2
    {
        long long thr = (long long)N_NODES * 64;
        k_agg2c<<<(unsigned)((thr + 255) / 256), 256, 0, stream>>>(cnt, csr, tb, wts, z);
    }

    {
        long long thr = (long long)N_LABEL * 16;
        k_decode<<<(unsigned)((thr + 255) / 256), 256, 0, stream>>>(eli, z, d_out, flags);
    }
}

// Round 7
// 279.491 us; speedup vs baseline: 1.0693x; 1.0693x over previous
//
#include <hip/hip_runtime.h>

#define N_NODES 100000
#define N_EDGES 640000
#define N_LABEL 100000
#define CAP 32   // max stored neighbors/node; deg ~Poisson(6.4) -> P(deg>32) ~ 1e-14
// IN_C=128, HID_C=128, OUT_C=64

typedef __bf16 bf16x8 __attribute__((ext_vector_type(8)));
typedef float f32x4 __attribute__((ext_vector_type(4)));

// canonical bf16 weight offsets (in shorts) inside ws weight region
#define CW1L 0
#define CB1  16384
#define CW1R 16512
#define CW2L 32896
#define CB2  41088
#define CW2R 41152
#define NWTS 49344

__device__ __forceinline__ float bf2f(unsigned short u) {
    union { unsigned int i; float f; } c; c.i = ((unsigned int)u) << 16; return c.f;
}
__device__ __forceinline__ unsigned short f2bf(float f) {
    union { float f; unsigned int i; } c; c.f = f;
    unsigned int lsb = (c.i >> 16) & 1u;
    c.i += 0x7fffu + lsb;              // round-to-nearest-even
    return (unsigned short)(c.i >> 16);
}

// ---- dtype detection: flags[0]=1 if x is f32 storage; flags[1]=1 if edges are int64 ----
__global__ void k_detect(const unsigned int* __restrict__ xw,
                         const unsigned int* __restrict__ eiw,
                         int* __restrict__ flags) {
    int l = threadIdx.x;
    unsigned int w = xw[l];
    unsigned short lo = (unsigned short)(w & 0xffffu);
    int e = (lo >> 7) & 0xff;
    bool bf_like = (lo == 0) || (e >= 98 && e <= 138);
    unsigned long long m = __ballot(bf_like);
    unsigned int ew = eiw[2 * l + 1];
    unsigned long long mz = __ballot(ew == 0u);
    if (l == 0) {
        flags[0] = (__popcll(m) < 48) ? 1 : 0;
        flags[1] = (__popcll(mz) == 64) ? 1 : 0;
    }
}

// ---- canonicalize weights/biases to bf16 ----
__global__ void k_convw(const void* W1l, const void* b1, const void* W1r,
                        const void* W2l, const void* b2, const void* W2r,
                        unsigned short* __restrict__ wts, const int* __restrict__ flags) {
    int i = blockIdx.x * blockDim.x + threadIdx.x;
    if (i >= NWTS) return;
    int f32m = flags[0];
    const void* src; int local;
    if      (i < CB1)  { src = W1l; local = i; }
    else if (i < CW1R) { src = b1;  local = i - CB1; }
    else if (i < CW2L) { src = W1r; local = i - CW1R; }
    else if (i < CB2)  { src = W2l; local = i - CW2L; }
    else if (i < CW2R) { src = b2;  local = i - CB2; }
    else               { src = W2r; local = i - CW2R; }
    wts[i] = f32m ? f2bf(((const float*)src)[local]) : ((const unsigned short*)src)[local];
}

// ---- canonicalize x -> bf16 xb (4 elems/thread) ----
__global__ void k_convx(const void* __restrict__ x, unsigned short* __restrict__ xb,
                        const int* __restrict__ flags) {
    int i = blockIdx.x * blockDim.x + threadIdx.x;
    if (i >= N_NODES * 32) return;   // 12.8M / 4
    if (flags[0]) {
        float4 p = ((const float4*)x)[i];
        ushort4 o;
        o.x = f2bf(p.x); o.y = f2bf(p.y); o.z = f2bf(p.z); o.w = f2bf(p.w);
        ((ushort4*)xb)[i] = o;
    } else {
        ((ushort4*)xb)[i] = ((const ushort4*)x)[i];
    }
}

// ---- build fixed-cap adjacency-by-dst: cnt[dst]++, csr[dst*CAP+pos]=src ----
__global__ void k_fill(const int* __restrict__ ei, int* __restrict__ cnt,
                       int* __restrict__ csr, const int* __restrict__ flags) {
    int e = blockIdx.x * blockDim.x + threadIdx.x;
    if (e >= N_EDGES) return;
    int i64 = flags[1];
    int src = ei[e << i64], dst = ei[(N_EDGES + e) << i64];
    int pos = atomicAdd(&cnt[dst], 1);
    if (pos < CAP) csr[dst * CAP + pos] = src;
}

// ---- fused agg1 + GEMM1: block = 4 waves = 32 nodes.
//  phase A: aggregate mean features into LDS (each wave: 8 nodes, 4-edge x 16-lane x 8ch gather)
//  phase B: each wave = one out-quarter (32 ch), 2 node-tiles, W-stationary MFMA ----
__global__ __launch_bounds__(256) void k_gemm1f(
    const int* __restrict__ cnt, const int* __restrict__ csr,
    const unsigned short* __restrict__ xb, const unsigned short* __restrict__ wts,
    unsigned short* __restrict__ h)
{
    __shared__ unsigned short smean[32][136];  // 272B row stride: 2-way LDS banks only
    int wave = threadIdx.x >> 6, lane = threadIdx.x & 63;
    int nb0 = blockIdx.x * 32;

    // ---------- phase A ----------
    int nA = nb0 + wave * 8;
    int half = lane >> 5, sl = lane & 31;
    int rows[4];
#pragma unroll
    for (int p = 0; p < 4; ++p)
        rows[p] = csr[(size_t)(nA + p * 2 + half) * CAP + sl];   // 2 csr rows per load
    int dpre = (lane < 8) ? cnt[nA + lane] : 0;
    int g = lane >> 4, q = lane & 15;
#pragma unroll
    for (int j = 0; j < 8; ++j) {
        int deg = __shfl(dpre, j);
        int m = deg < CAP ? deg : CAP;
        int srcrow = rows[j >> 1];
        int ebase = (j & 1) * 32;
        float s[8];
#pragma unroll
        for (int jj = 0; jj < 8; ++jj) s[jj] = 0.f;
        for (int e0 = 0; e0 < m; e0 += 4) {
            int e = e0 + g;
            int sidx = __shfl(srcrow, ebase + e);
            if (e < m) {
                uint4 w = *(const uint4*)(xb + (size_t)sidx * 128 + q * 8);
                s[0] += bf2f((unsigned short)w.x); s[1] += bf2f((unsigned short)(w.x >> 16));
                s[2] += bf2f((unsigned short)w.y); s[3] += bf2f((unsigned short)(w.y >> 16));
                s[4] += bf2f((unsigned short)w.z); s[5] += bf2f((unsigned short)(w.z >> 16));
                s[6] += bf2f((unsigned short)w.w); s[7] += bf2f((unsigned short)(w.w >> 16));
            }
        }
#pragma unroll
        for (int off = 16; off < 64; off <<= 1)
#pragma unroll
            for (int jj = 0; jj < 8; ++jj) s[jj] += __shfl_xor(s[jj], off);
        if (g == 0) {
            float inv = 1.0f / (deg > 1 ? (float)deg : 1.0f);
            uint4 o;
            o.x = (unsigned int)f2bf(s[0] * inv) | ((unsigned int)f2bf(s[1] * inv) << 16);
            o.y = (unsigned int)f2bf(s[2] * inv) | ((unsigned int)f2bf(s[3] * inv) << 16);
            o.z = (unsigned int)f2bf(s[4] * inv) | ((unsigned int)f2bf(s[5] * inv) << 16);
            o.w = (unsigned int)f2bf(s[6] * inv) | ((unsigned int)f2bf(s[7] * inv) << 16);
            *(uint4*)&smean[wave * 8 + j][q * 8] = o;
        }
    }
    __syncthreads();

    // ---------- phase B ----------
    int qq = wave;                      // out-channel quarter: ch [qq*32, qq*32+32)
    int row = lane & 15, kq = lane >> 4;
    bf16x8 Wf[16];                      // 2 out-tiles x 8 k-steps (K=256)
#pragma unroll
    for (int t = 0; t < 2; ++t)
#pragma unroll
        for (int ks = 0; ks < 8; ++ks) {
            const int k0 = ks * 32;
            const unsigned short* base = wts + (k0 < 128 ? CW1L : CW1R)
                + (size_t)(qq * 32 + t * 16 + row) * 128 + (k0 & 127) + kq * 8;
            Wf[t * 8 + ks] = *reinterpret_cast<const bf16x8*>(base);
        }
    int col = lane & 15, rq = lane >> 4;
    float bias0 = bf2f(wts[CB1 + qq * 32 + col]);
    float bias1 = bf2f(wts[CB1 + qq * 32 + 16 + col]);

#pragma unroll
    for (int i = 0; i < 2; ++i) {
        int n0 = nb0 + i * 16;
        bf16x8 Af[8];
#pragma unroll
        for (int ks = 0; ks < 4; ++ks)
            Af[ks] = *reinterpret_cast<const bf16x8*>(&smean[i * 16 + row][ks * 32 + kq * 8]);
        const unsigned short* rx = xb + (size_t)(n0 + row) * 128 + kq * 8;
#pragma unroll
        for (int ks = 0; ks < 4; ++ks)
            Af[4 + ks] = *reinterpret_cast<const bf16x8*>(rx + ks * 32);
        f32x4 acc0 = (f32x4){0.f, 0.f, 0.f, 0.f};
        f32x4 acc1 = (f32x4){0.f, 0.f, 0.f, 0.f};
#pragma unroll
        for (int ks = 0; ks < 8; ++ks) {
            acc0 = __builtin_amdgcn_mfma_f32_16x16x32_bf16(Af[ks], Wf[ks],     acc0, 0, 0, 0);
            acc1 = __builtin_amdgcn_mfma_f32_16x16x32_bf16(Af[ks], Wf[8 + ks], acc1, 0, 0, 0);
        }
#pragma unroll
        for (int r = 0; r < 4; ++r) {
            int n = n0 + rq * 4 + r;
            float v0 = acc0[r] + bias0; v0 = v0 > 0.f ? v0 : 0.f;
            float v1 = acc1[r] + bias1; v1 = v1 > 0.f ? v1 : 0.f;
            h[(size_t)n * 128 + qq * 32 + col]      = f2bf(v0);
            h[(size_t)n * 128 + qq * 32 + 16 + col] = f2bf(v1);
        }
    }
}

// ---- GEMM2: W-stationary, 2 tiles/wave. Wave = out-quarter (32ch of [t_l||t_r]) ----
__global__ __launch_bounds__(256) void k_gemm2(
    const unsigned short* __restrict__ h, const unsigned short* __restrict__ wts,
    unsigned short* __restrict__ tb)
{
    int w = (int)((blockIdx.x * blockDim.x + threadIdx.x) >> 6);
    int lane = threadIdx.x & 63;
    int q = w & 3;          // out quarter: q<2 -> W2l (t_l), q>=2 -> W2r (t_r)
    int tg = w >> 2;
    int row = lane & 15, kq = lane >> 4;

    const size_t wbase = (q < 2) ? (CW2L + (size_t)(q * 32) * 128)
                                 : (CW2R + (size_t)((q - 2) * 32) * 128);
    bf16x8 Wf[8];           // 2 out-tiles x 4 k-steps (K=128)
#pragma unroll
    for (int t = 0; t < 2; ++t)
#pragma unroll
        for (int ks = 0; ks < 4; ++ks)
            Wf[t * 4 + ks] = *reinterpret_cast<const bf16x8*>(
                wts + wbase + (size_t)(t * 16 + row) * 128 + ks * 32 + kq * 8);

    int col = lane & 15, rq = lane >> 4;
    int nt0 = tg * 2;
    bf16x8 Af[2][4];

#define LOAD_A2(tile, buf)                                                            \
    {                                                                                 \
        int n0_ = (tile) * 16;                                                        \
        if (n0_ < N_NODES) {                                                          \
            const unsigned short* rh = h + (size_t)(n0_ + row) * 128 + kq * 8;        \
            _Pragma("unroll")                                                         \
            for (int ks = 0; ks < 4; ++ks)                                            \
                Af[buf][ks] = *reinterpret_cast<const bf16x8*>(rh + ks * 32);         \
        }                                                                             \
    }

    LOAD_A2(nt0, 0);
#pragma unroll
    for (int i = 0; i < 2; ++i) {
        int n0 = (nt0 + i) * 16;
        if (n0 >= N_NODES) continue;
        if (i < 1) LOAD_A2(nt0 + i + 1, (i + 1) & 1);
        f32x4 acc0 = (f32x4){0.f, 0.f, 0.f, 0.f};
        f32x4 acc1 = (f32x4){0.f, 0.f, 0.f, 0.f};
#pragma unroll
        for (int ks = 0; ks < 4; ++ks) {
            acc0 = __builtin_amdgcn_mfma_f32_16x16x32_bf16(Af[i & 1][ks], Wf[ks],     acc0, 0, 0, 0);
            acc1 = __builtin_amdgcn_mfma_f32_16x16x32_bf16(Af[i & 1][ks], Wf[4 + ks], acc1, 0, 0, 0);
        }
#pragma unroll
        for (int r = 0; r < 4; ++r) {
            int n = n0 + rq * 4 + r;
            tb[(size_t)n * 128 + q * 32 + col]      = f2bf(acc0[r]);
            tb[(size_t)n * 128 + q * 32 + 16 + col] = f2bf(acc1[r]);
        }
    }
#undef LOAD_A2
}

// ---- layer-2 gather + combine: z = agg(t_l)/deg + b2 + t_r. 8 edges x 8 lanes x 8ch ----
__global__ __launch_bounds__(256) void k_agg2c(
    const int* __restrict__ cnt, const int* __restrict__ csr,
    const unsigned short* __restrict__ tb, const unsigned short* __restrict__ wts,
    float* __restrict__ z) {
    int n = (int)((blockIdx.x * blockDim.x + threadIdx.x) >> 6);
    if (n >= N_NODES) return;
    int lane = threadIdx.x & 63;
    int g = lane >> 3, q = lane & 7;
    int deg = cnt[n];
    int m = deg < CAP ? deg : CAP;
    int srcl = (lane < m) ? csr[(size_t)n * CAP + lane] : 0;
    float s[8];
#pragma unroll
    for (int j = 0; j < 8; ++j) s[j] = 0.f;
    for (int e0 = 0; e0 < m; e0 += 8) {
        int e = e0 + g;
        int sidx = __shfl(srcl, e);
        if (e < m) {
            uint4 w = *(const uint4*)(tb + (size_t)sidx * 128 + q * 8);
            s[0] += bf2f((unsigned short)w.x); s[1] += bf2f((unsigned short)(w.x >> 16));
            s[2] += bf2f((unsigned short)w.y); s[3] += bf2f((unsigned short)(w.y >> 16));
            s[4] += bf2f((unsigned short)w.z); s[5] += bf2f((unsigned short)(w.z >> 16));
            s[6] += bf2f((unsigned short)w.w); s[7] += bf2f((unsigned short)(w.w >> 16));
        }
    }
#pragma unroll
    for (int off = 8; off < 64; off <<= 1)
#pragma unroll
        for (int j = 0; j < 8; ++j) s[j] += __shfl_xor(s[j], off);
    if (g == 0) {
        float inv = 1.0f / (deg > 1 ? (float)deg : 1.0f);
        uint4 tr = *(const uint4*)(tb + (size_t)n * 128 + 64 + q * 8);
        uint4 bb = *(const uint4*)(wts + CB2 + q * 8);
        float4 z0, z1;
        z0.x = s[0] * inv + bf2f((unsigned short)bb.x)         + bf2f((unsigned short)tr.x);
        z0.y = s[1] * inv + bf2f((unsigned short)(bb.x >> 16)) + bf2f((unsigned short)(tr.x >> 16));
        z0.z = s[2] * inv + bf2f((unsigned short)bb.y)         + bf2f((unsigned short)tr.y);
        z0.w = s[3] * inv + bf2f((unsigned short)(bb.y >> 16)) + bf2f((unsigned short)(tr.y >> 16));
        z1.x = s[4] * inv + bf2f((unsigned short)bb.z)         + bf2f((unsigned short)tr.z);
        z1.y = s[5] * inv + bf2f((unsigned short)(bb.z >> 16)) + bf2f((unsigned short)(tr.z >> 16));
        z1.z = s[6] * inv + bf2f((unsigned short)bb.w)         + bf2f((unsigned short)tr.w);
        z1.w = s[7] * inv + bf2f((unsigned short)(bb.w >> 16)) + bf2f((unsigned short)(tr.w >> 16));
        *(float4*)(z + (size_t)n * 64 + q * 8)     = z0;
        *(float4*)(z + (size_t)n * 64 + q * 8 + 4) = z1;
    }
}

// ---- decode: scores[e] = dot64(z[a], z[b]); 4 edges/wave, 16 lanes x float4 ----
__global__ void k_decode(const int* __restrict__ eli, const float* __restrict__ z,
                         void* __restrict__ out, const int* __restrict__ flags) {
    long long t = (long long)blockIdx.x * blockDim.x + threadIdx.x;
    int e = (int)(t >> 4);
    if (e >= N_LABEL) return;
    int f32m = flags[0], i64 = flags[1];
    int q = threadIdx.x & 15;
    int a = eli[e << i64], b = eli[(N_LABEL + e) << i64];
    float4 pa = *(const float4*)(z + (size_t)a * 64 + q * 4);
    float4 pb = *(const float4*)(z + (size_t)b * 64 + q * 4);
    float s = pa.x * pb.x + pa.y * pb.y + pa.z * pb.z + pa.w * pb.w;
#pragma unroll
    for (int off = 1; off < 16; off <<= 1) s += __shfl_xor(s, off);
    if (q == 0) {
        if (f32m) ((float*)out)[e] = s;
        else      ((unsigned short*)out)[e] = f2bf(s);
    }
}

extern "C" void kernel_launch(void* const* d_in, const int* in_sizes, int n_in,
                              void* d_out, int out_size, void* d_ws, size_t ws_size,
                              hipStream_t stream) {
    const void* x   = d_in[0];
    const int*  ei  = (const int*)d_in[1];
    const int*  eli = (const int*)d_in[2];
    const void* W1l = d_in[3];
    const void* b1  = d_in[4];
    const void* W1r = d_in[5];
    const void* W2l = d_in[6];
    const void* b2  = d_in[7];
    const void* W2r = d_in[8];

    char* ws = (char*)d_ws;
    const size_t offFlag = 0;
    const size_t offCnt  = 1024;                       // int[100000] -> 400 KB
    const size_t offWts  = 801024;                     // bf16[NWTS]  -> ~96 KB
    const size_t offCsr  = 1u << 20;                              // int[N*32]    12.8 MB
    const size_t offXb   = offCsr + (size_t)N_NODES * CAP * 4;    // xb bf16[N,128] 25.6 MB
    const size_t offTb   = offXb  + (size_t)N_NODES * 128 * 2;    // tb bf16[N,128] 25.6 MB
    const size_t offHz   = offTb  + (size_t)N_NODES * 128 * 2;    // h bf16 -> z f32[N,64]
    // total = 1 MB + 12.8 + 3*25.6 = 90.6 MB (below proven 103.4 MB footprint)

    int*            flags = (int*)(ws + offFlag);
    int*            cnt   = (int*)(ws + offCnt);
    unsigned short* wts   = (unsigned short*)(ws + offWts);
    int*            csr   = (int*)(ws + offCsr);
    unsigned short* xb    = (unsigned short*)(ws + offXb);
    unsigned short* tb    = (unsigned short*)(ws + offTb);
    unsigned short* h     = (unsigned short*)(ws + offHz);

    hipMemsetAsync(ws, 0, 1u << 20, stream);   // flags + cnt (wts rewritten anyway)

    k_detect<<<1, 64, 0, stream>>>((const unsigned int*)x, (const unsigned int*)ei, flags);
    k_convw<<<(NWTS + 255) / 256, 256, 0, stream>>>(W1l, b1, W1r, W2l, b2, W2r, wts, flags);
    k_convx<<<(N_NODES * 32 + 255) / 256, 256, 0, stream>>>(x, xb, flags);
    k_fill<<<(N_EDGES + 255) / 256, 256, 0, stream>>>(ei, cnt, csr, flags);

    // fused agg1+gemm1: 32 nodes/block, 100000/32 = 3125 blocks exactly
    k_gemm1f<<<N_NODES / 32, 256, 0, stream>>>(cnt, csr, xb, wts, h);

    // gemm2: node-tiles = 6250; groups of 2 = 3125; x4 quarters = 3125 blocks
    k_gemm2<<<3125, 256, 0, stream>>>(h, wts, tb);

    float* z = (float*)(ws + offHz);  // h dead after gemm2
    {
        long long thr = (long long)N_NODES * 64;
        k_agg2c<<<(unsigned)((thr + 255) / 256), 256, 0, stream>>>(cnt, csr, tb, wts, z);
    }

    {
        long long thr = (long long)N_LABEL * 16;
        k_decode<<<(unsigned)((thr + 255) / 256), 256, 0, stream>>>(eli, z, d_out, flags);
    }
}

// Round 8
// 259.311 us; speedup vs baseline: 1.1525x; 1.0778x over previous
//
#include <hip/hip_runtime.h>

#define N_NODES 100000
#define N_EDGES 640000
#define N_LABEL 100000
#define CAP 32   // max stored neighbors/node; deg ~Poisson(6.4) -> P(deg>32) ~ 1e-14
// IN_C=128, HID_C=128, OUT_C=64

typedef __bf16 bf16x8 __attribute__((ext_vector_type(8)));
typedef float f32x4 __attribute__((ext_vector_type(4)));

// canonical bf16 weight offsets (in shorts) inside ws weight region
#define CW1L 0
#define CB1  16384
#define CW1R 16512
#define CW2L 32896
#define CB2  41088
#define CW2R 41152
#define NWTS 49344

// fused convw|convx block split (both pure streaming)
#define NB_W 193
#define NB_X 12500

__device__ __forceinline__ float bf2f(unsigned short u) {
    union { unsigned int i; float f; } c; c.i = ((unsigned int)u) << 16; return c.f;
}
__device__ __forceinline__ unsigned short f2bf(float f) {
    union { float f; unsigned int i; } c; c.f = f;
    unsigned int lsb = (c.i >> 16) & 1u;
    c.i += 0x7fffu + lsb;              // round-to-nearest-even
    return (unsigned short)(c.i >> 16);
}

// ---- dtype detection: flags[0]=1 if x is f32 storage; flags[1]=1 if edges are int64 ----
__global__ void k_detect(const unsigned int* __restrict__ xw,
                         const unsigned int* __restrict__ eiw,
                         int* __restrict__ flags) {
    int l = threadIdx.x;
    unsigned int w = xw[l];
    unsigned short lo = (unsigned short)(w & 0xffffu);
    int e = (lo >> 7) & 0xff;
    bool bf_like = (lo == 0) || (e >= 98 && e <= 138);
    unsigned long long m = __ballot(bf_like);
    unsigned int ew = eiw[2 * l + 1];
    unsigned long long mz = __ballot(ew == 0u);
    if (l == 0) {
        flags[0] = (__popcll(m) < 48) ? 1 : 0;
        flags[1] = (__popcll(mz) == 64) ? 1 : 0;
    }
}

// ---- fused streaming canonicalize: weights -> bf16 wts | x -> bf16 xb ----
__global__ void k_convwx(const void* W1l, const void* b1, const void* W1r,
                         const void* W2l, const void* b2, const void* W2r,
                         unsigned short* __restrict__ wts,
                         const void* __restrict__ x, unsigned short* __restrict__ xb,
                         const int* __restrict__ flags) {
    int b = blockIdx.x;
    int f32m = flags[0];
    if (b < NB_W) {
        int i = b * 256 + threadIdx.x;
        if (i >= NWTS) return;
        const void* src; int local;
        if      (i < CB1)  { src = W1l; local = i; }
        else if (i < CW1R) { src = b1;  local = i - CB1; }
        else if (i < CW2L) { src = W1r; local = i - CW1R; }
        else if (i < CB2)  { src = W2l; local = i - CW2L; }
        else if (i < CW2R) { src = b2;  local = i - CB2; }
        else               { src = W2r; local = i - CW2R; }
        wts[i] = f32m ? f2bf(((const float*)src)[local]) : ((const unsigned short*)src)[local];
    } else {
        int i = (b - NB_W) * 256 + threadIdx.x;
        if (i >= N_NODES * 32) return;   // 12.8M / 4
        if (f32m) {
            float4 p = ((const float4*)x)[i];
            ushort4 o;
            o.x = f2bf(p.x); o.y = f2bf(p.y); o.z = f2bf(p.z); o.w = f2bf(p.w);
            ((ushort4*)xb)[i] = o;
        } else {
            ((ushort4*)xb)[i] = ((const ushort4*)x)[i];
        }
    }
}

// ---- build fixed-cap adjacency-by-dst: cnt[dst]++, csr[dst*CAP+pos]=src ----
__global__ void k_fill(const int* __restrict__ ei, int* __restrict__ cnt,
                       int* __restrict__ csr, const int* __restrict__ flags) {
    int e = blockIdx.x * blockDim.x + threadIdx.x;
    if (e >= N_EDGES) return;
    int i64 = flags[1];
    int src = ei[e << i64], dst = ei[(N_EDGES + e) << i64];
    int pos = atomicAdd(&cnt[dst], 1);
    if (pos < CAP) csr[dst * CAP + pos] = src;
}

// ---- fused agg1 + GEMM1: block = 4 waves = 32 nodes.
//  phase A: per-lane 2-channel gather, 8-deep always-issued loads, NO cross-lane reduce
//  phase B: each wave = one out-quarter (32 ch), 2 node-tiles, W-stationary MFMA ----
__global__ __launch_bounds__(256) void k_gemm1f(
    const int* __restrict__ cnt, const int* __restrict__ csr,
    const unsigned short* __restrict__ xb, const unsigned short* __restrict__ wts,
    unsigned short* __restrict__ h)
{
    __shared__ unsigned short smean[32][136];  // 272B row stride
    int wave = threadIdx.x >> 6, lane = threadIdx.x & 63;
    int nb0 = blockIdx.x * 32;

    // ---------- phase A: wave handles 8 nodes, lane owns channels 2l,2l+1 ----------
    int nA = nb0 + wave * 8;
    int half = lane >> 5, sl = lane & 31;
    int rows[4];
#pragma unroll
    for (int p = 0; p < 4; ++p)
        rows[p] = csr[(size_t)(nA + p * 2 + half) * CAP + sl];   // 2 csr rows per reg
    int dpre = (lane < 8) ? cnt[nA + lane] : 0;
    int c2 = lane << 1;

#pragma unroll
    for (int j = 0; j < 8; ++j) {
        int deg = __shfl(dpre, j);
        int m = deg < CAP ? deg : CAP;
        float s0 = 0.f, s1 = 0.f;
        for (int e0 = 0; e0 < m; e0 += 8) {
            unsigned int v[8];
#pragma unroll
            for (int u = 0; u < 8; ++u) {
                int e = e0 + u;
                int sidx = __shfl(rows[j >> 1], (j & 1) * 32 + e);
                sidx = (e < m) ? sidx : 0;                       // clamp: always load
                v[u] = *(const unsigned int*)(xb + (size_t)sidx * 128 + c2);
            }
#pragma unroll
            for (int u = 0; u < 8; ++u) {
                bool ok = (e0 + u) < m;
                s0 += ok ? bf2f((unsigned short)(v[u] & 0xffffu)) : 0.f;
                s1 += ok ? bf2f((unsigned short)(v[u] >> 16)) : 0.f;
            }
        }
        float inv = 1.0f / (deg > 1 ? (float)deg : 1.0f);
        unsigned int o = (unsigned int)f2bf(s0 * inv) | ((unsigned int)f2bf(s1 * inv) << 16);
        *(unsigned int*)&smean[wave * 8 + j][c2] = o;
    }
    __syncthreads();

    // ---------- phase B ----------
    int qq = wave;                      // out-channel quarter: ch [qq*32, qq*32+32)
    int row = lane & 15, kq = lane >> 4;
    bf16x8 Wf[16];                      // 2 out-tiles x 8 k-steps (K=256)
#pragma unroll
    for (int t = 0; t < 2; ++t)
#pragma unroll
        for (int ks = 0; ks < 8; ++ks) {
            const int k0 = ks * 32;
            const unsigned short* base = wts + (k0 < 128 ? CW1L : CW1R)
                + (size_t)(qq * 32 + t * 16 + row) * 128 + (k0 & 127) + kq * 8;
            Wf[t * 8 + ks] = *reinterpret_cast<const bf16x8*>(base);
        }
    int col = lane & 15, rq = lane >> 4;
    float bias0 = bf2f(wts[CB1 + qq * 32 + col]);
    float bias1 = bf2f(wts[CB1 + qq * 32 + 16 + col]);

#pragma unroll
    for (int i = 0; i < 2; ++i) {
        int n0 = nb0 + i * 16;
        bf16x8 Af[8];
#pragma unroll
        for (int ks = 0; ks < 4; ++ks)
            Af[ks] = *reinterpret_cast<const bf16x8*>(&smean[i * 16 + row][ks * 32 + kq * 8]);
        const unsigned short* rx = xb + (size_t)(n0 + row) * 128 + kq * 8;
#pragma unroll
        for (int ks = 0; ks < 4; ++ks)
            Af[4 + ks] = *reinterpret_cast<const bf16x8*>(rx + ks * 32);
        f32x4 acc0 = (f32x4){0.f, 0.f, 0.f, 0.f};
        f32x4 acc1 = (f32x4){0.f, 0.f, 0.f, 0.f};
#pragma unroll
        for (int ks = 0; ks < 8; ++ks) {
            acc0 = __builtin_amdgcn_mfma_f32_16x16x32_bf16(Af[ks], Wf[ks],     acc0, 0, 0, 0);
            acc1 = __builtin_amdgcn_mfma_f32_16x16x32_bf16(Af[ks], Wf[8 + ks], acc1, 0, 0, 0);
        }
#pragma unroll
        for (int r = 0; r < 4; ++r) {
            int n = n0 + rq * 4 + r;
            float v0 = acc0[r] + bias0; v0 = v0 > 0.f ? v0 : 0.f;
            float v1 = acc1[r] + bias1; v1 = v1 > 0.f ? v1 : 0.f;
            h[(size_t)n * 128 + qq * 32 + col]      = f2bf(v0);
            h[(size_t)n * 128 + qq * 32 + 16 + col] = f2bf(v1);
        }
    }
}

// ---- GEMM2: W-stationary, 2 tiles/wave. Wave = out-quarter (32ch of [t_l||t_r]) ----
__global__ __launch_bounds__(256) void k_gemm2(
    const unsigned short* __restrict__ h, const unsigned short* __restrict__ wts,
    unsigned short* __restrict__ tb)
{
    int w = (int)((blockIdx.x * blockDim.x + threadIdx.x) >> 6);
    int lane = threadIdx.x & 63;
    int q = w & 3;          // out quarter: q<2 -> W2l (t_l), q>=2 -> W2r (t_r)
    int tg = w >> 2;
    int row = lane & 15, kq = lane >> 4;

    const size_t wbase = (q < 2) ? (CW2L + (size_t)(q * 32) * 128)
                                 : (CW2R + (size_t)((q - 2) * 32) * 128);
    bf16x8 Wf[8];           // 2 out-tiles x 4 k-steps (K=128)
#pragma unroll
    for (int t = 0; t < 2; ++t)
#pragma unroll
        for (int ks = 0; ks < 4; ++ks)
            Wf[t * 4 + ks] = *reinterpret_cast<const bf16x8*>(
                wts + wbase + (size_t)(t * 16 + row) * 128 + ks * 32 + kq * 8);

    int col = lane & 15, rq = lane >> 4;
    int nt0 = tg * 2;
    bf16x8 Af[2][4];

#define LOAD_A2(tile, buf)                                                            \
    {                                                                                 \
        int n0_ = (tile) * 16;                                                        \
        if (n0_ < N_NODES) {                                                          \
            const unsigned short* rh = h + (size_t)(n0_ + row) * 128 + kq * 8;        \
            _Pragma("unroll")                                                         \
            for (int ks = 0; ks < 4; ++ks)                                            \
                Af[buf][ks] = *reinterpret_cast<const bf16x8*>(rh + ks * 32);         \
        }                                                                             \
    }

    LOAD_A2(nt0, 0);
#pragma unroll
    for (int i = 0; i < 2; ++i) {
        int n0 = (nt0 + i) * 16;
        if (n0 >= N_NODES) continue;
        if (i < 1) LOAD_A2(nt0 + i + 1, (i + 1) & 1);
        f32x4 acc0 = (f32x4){0.f, 0.f, 0.f, 0.f};
        f32x4 acc1 = (f32x4){0.f, 0.f, 0.f, 0.f};
#pragma unroll
        for (int ks = 0; ks < 4; ++ks) {
            acc0 = __builtin_amdgcn_mfma_f32_16x16x32_bf16(Af[i & 1][ks], Wf[ks],     acc0, 0, 0, 0);
            acc1 = __builtin_amdgcn_mfma_f32_16x16x32_bf16(Af[i & 1][ks], Wf[4 + ks], acc1, 0, 0, 0);
        }
#pragma unroll
        for (int r = 0; r < 4; ++r) {
            int n = n0 + rq * 4 + r;
            tb[(size_t)n * 128 + q * 32 + col]      = f2bf(acc0[r]);
            tb[(size_t)n * 128 + q * 32 + 16 + col] = f2bf(acc1[r]);
        }
    }
#undef LOAD_A2
}

// ---- layer-2 gather + combine: z = agg(t_l)/deg + b2 + t_r.
//  2 nodes/wave (half-wave each), lane owns 2 ch, 8-deep clamped loads, no reduce ----
__global__ __launch_bounds__(256) void k_agg2c(
    const int* __restrict__ cnt, const int* __restrict__ csr,
    const unsigned short* __restrict__ tb, const unsigned short* __restrict__ wts,
    float* __restrict__ z) {
    int wv = (int)((blockIdx.x * blockDim.x + threadIdx.x) >> 6);
    int n2 = wv * 2;
    if (n2 >= N_NODES) return;
    int lane = threadIdx.x & 63;
    int half = lane >> 5, sl = lane & 31;
    int n = n2 + half;                  // N_NODES even -> both halves valid
    int dpre = (lane < 2) ? cnt[n2 + lane] : 0;
    int deg = __shfl(dpre, half);
    int m = deg < CAP ? deg : CAP;
    int mo = __shfl(m, lane ^ 32);      // other half's m
    int mmax = m > mo ? m : mo;
    int srcrow = csr[(size_t)n * CAP + sl];
    int c2 = sl << 1;                   // channels 2sl, 2sl+1 of t_l
    float s0 = 0.f, s1 = 0.f;
    for (int e0 = 0; e0 < mmax; e0 += 8) {
        unsigned int v[8];
#pragma unroll
        for (int u = 0; u < 8; ++u) {
            int e = e0 + u;
            int sidx = __shfl(srcrow, half * 32 + e);
            sidx = (e < m) ? sidx : 0;
            v[u] = *(const unsigned int*)(tb + (size_t)sidx * 128 + c2);
        }
#pragma unroll
        for (int u = 0; u < 8; ++u) {
            bool ok = (e0 + u) < m;
            s0 += ok ? bf2f((unsigned short)(v[u] & 0xffffu)) : 0.f;
            s1 += ok ? bf2f((unsigned short)(v[u] >> 16)) : 0.f;
        }
    }
    float inv = 1.0f / (deg > 1 ? (float)deg : 1.0f);
    unsigned int tr = *(const unsigned int*)(tb + (size_t)n * 128 + 64 + c2);
    unsigned int bb = *(const unsigned int*)(wts + CB2 + c2);
    float2 o;
    o.x = s0 * inv + bf2f((unsigned short)(bb & 0xffffu)) + bf2f((unsigned short)(tr & 0xffffu));
    o.y = s1 * inv + bf2f((unsigned short)(bb >> 16))     + bf2f((unsigned short)(tr >> 16));
    *(float2*)(z + (size_t)n * 64 + c2) = o;
}

// ---- decode: scores[e] = dot64(z[a], z[b]); 4 edges/wave, 16 lanes x float4 ----
__global__ void k_decode(const int* __restrict__ eli, const float* __restrict__ z,
                         void* __restrict__ out, const int* __restrict__ flags) {
    long long t = (long long)blockIdx.x * blockDim.x + threadIdx.x;
    int e = (int)(t >> 4);
    if (e >= N_LABEL) return;
    int f32m = flags[0], i64 = flags[1];
    int q = threadIdx.x & 15;
    int a = eli[e << i64], b = eli[(N_LABEL + e) << i64];
    float4 pa = *(const float4*)(z + (size_t)a * 64 + q * 4);
    float4 pb = *(const float4*)(z + (size_t)b * 64 + q * 4);
    float s = pa.x * pb.x + pa.y * pb.y + pa.z * pb.z + pa.w * pb.w;
#pragma unroll
    for (int off = 1; off < 16; off <<= 1) s += __shfl_xor(s, off);
    if (q == 0) {
        if (f32m) ((float*)out)[e] = s;
        else      ((unsigned short*)out)[e] = f2bf(s);
    }
}

extern "C" void kernel_launch(void* const* d_in, const int* in_sizes, int n_in,
                              void* d_out, int out_size, void* d_ws, size_t ws_size,
                              hipStream_t stream) {
    const void* x   = d_in[0];
    const int*  ei  = (const int*)d_in[1];
    const int*  eli = (const int*)d_in[2];
    const void* W1l = d_in[3];
    const void* b1  = d_in[4];
    const void* W1r = d_in[5];
    const void* W2l = d_in[6];
    const void* b2  = d_in[7];
    const void* W2r = d_in[8];

    char* ws = (char*)d_ws;
    const size_t offFlag = 0;
    const size_t offCnt  = 1024;                       // int[100000] -> 400 KB
    const size_t offWts  = 801024;                     // bf16[NWTS]  -> ~96 KB
    const size_t offCsr  = 1u << 20;                              // int[N*32]    12.8 MB
    const size_t offXb   = offCsr + (size_t)N_NODES * CAP * 4;    // xb bf16[N,128] 25.6 MB
    const size_t offTb   = offXb  + (size_t)N_NODES * 128 * 2;    // tb bf16[N,128] 25.6 MB
    const size_t offHz   = offTb  + (size_t)N_NODES * 128 * 2;    // h bf16 -> z f32[N,64]
    // total = 1 MB + 12.8 + 3*25.6 = 90.6 MB

    int*            flags = (int*)(ws + offFlag);
    int*            cnt   = (int*)(ws + offCnt);
    unsigned short* wts   = (unsigned short*)(ws + offWts);
    int*            csr   = (int*)(ws + offCsr);
    unsigned short* xb    = (unsigned short*)(ws + offXb);
    unsigned short* tb    = (unsigned short*)(ws + offTb);
    unsigned short* h     = (unsigned short*)(ws + offHz);

    hipMemsetAsync(ws, 0, 1u << 20, stream);   // flags + cnt (wts rewritten anyway)

    k_detect<<<1, 64, 0, stream>>>((const unsigned int*)x, (const unsigned int*)ei, flags);

    // fused streaming canonicalize (weights + x)
    k_convwx<<<NB_W + NB_X, 256, 0, stream>>>(W1l, b1, W1r, W2l, b2, W2r, wts, x, xb, flags);

    k_fill<<<(N_EDGES + 255) / 256, 256, 0, stream>>>(ei, cnt, csr, flags);

    // fused agg1+gemm1: 32 nodes/block, 100000/32 = 3125 blocks exactly
    k_gemm1f<<<N_NODES / 32, 256, 0, stream>>>(cnt, csr, xb, wts, h);

    // gemm2: node-tiles = 6250; groups of 2 = 3125; x4 quarters = 3125 blocks
    k_gemm2<<<3125, 256, 0, stream>>>(h, wts, tb);

    float* z = (float*)(ws + offHz);  // h dead after gemm2
    // agg2c: 2 nodes/wave -> 50000 waves -> 12500 blocks
    k_agg2c<<<12500, 256, 0, stream>>>(cnt, csr, tb, wts, z);

    {
        long long thr = (long long)N_LABEL * 16;
        k_decode<<<(unsigned)((thr + 255) / 256), 256, 0, stream>>>(eli, z, d_out, flags);
    }
}

// Round 9
// 232.674 us; speedup vs baseline: 1.2844x; 1.1145x over previous
//
#include <hip/hip_runtime.h>

#define N_NODES 100000
#define N_EDGES 640000
#define N_LABEL 100000
#define CAP 32   // max stored neighbors/node; deg ~Poisson(6.4) -> P(any>32) ~ 1e-9
// IN_C=128, HID_C=128, OUT_C=64

typedef __bf16 bf16x8 __attribute__((ext_vector_type(8)));
typedef float f32x4 __attribute__((ext_vector_type(4)));

// canonical bf16 weight offsets (in shorts) inside ws weight region
#define CW1L 0
#define CB1  16384
#define CW1R 16512
#define CW2L 32896
#define CB2  41088
#define CW2R 41152
#define NWTS 49344

// fused convw|convx block split (both pure streaming)
#define NB_W 193
#define NB_X 12500

__device__ __forceinline__ float bf2f(unsigned short u) {
    union { unsigned int i; float f; } c; c.i = ((unsigned int)u) << 16; return c.f;
}
__device__ __forceinline__ float asf(unsigned int u) {
    union { unsigned int i; float f; } c; c.i = u; return c.f;
}
__device__ __forceinline__ unsigned short f2bf(float f) {
    union { float f; unsigned int i; } c; c.f = f;
    unsigned int lsb = (c.i >> 16) & 1u;
    c.i += 0x7fffu + lsb;              // round-to-nearest-even
    return (unsigned short)(c.i >> 16);
}

// ---- dtype detection: flags[0]=1 if x is f32 storage; flags[1]=1 if edges are int64 ----
__global__ void k_detect(const unsigned int* __restrict__ xw,
                         const unsigned int* __restrict__ eiw,
                         int* __restrict__ flags) {
    int l = threadIdx.x;
    unsigned int w = xw[l];
    unsigned short lo = (unsigned short)(w & 0xffffu);
    int e = (lo >> 7) & 0xff;
    bool bf_like = (lo == 0) || (e >= 98 && e <= 138);
    unsigned long long m = __ballot(bf_like);
    unsigned int ew = eiw[2 * l + 1];
    unsigned long long mz = __ballot(ew == 0u);
    if (l == 0) {
        flags[0] = (__popcll(m) < 48) ? 1 : 0;
        flags[1] = (__popcll(mz) == 64) ? 1 : 0;
    }
}

// ---- fused streaming canonicalize: weights -> bf16 wts | x -> bf16 xb ----
__global__ void k_convwx(const void* W1l, const void* b1, const void* W1r,
                         const void* W2l, const void* b2, const void* W2r,
                         unsigned short* __restrict__ wts,
                         const void* __restrict__ x, unsigned short* __restrict__ xb,
                         const int* __restrict__ flags) {
    int b = blockIdx.x;
    int f32m = flags[0];
    if (b < NB_W) {
        int i = b * 256 + threadIdx.x;
        if (i >= NWTS) return;
        const void* src; int local;
        if      (i < CB1)  { src = W1l; local = i; }
        else if (i < CW1R) { src = b1;  local = i - CB1; }
        else if (i < CW2L) { src = W1r; local = i - CW1R; }
        else if (i < CB2)  { src = W2l; local = i - CW2L; }
        else if (i < CW2R) { src = b2;  local = i - CB2; }
        else               { src = W2r; local = i - CW2R; }
        wts[i] = f32m ? f2bf(((const float*)src)[local]) : ((const unsigned short*)src)[local];
    } else {
        int i = (b - NB_W) * 256 + threadIdx.x;
        if (i >= N_NODES * 32) return;   // 12.8M / 4
        if (f32m) {
            float4 p = ((const float4*)x)[i];
            ushort4 o;
            o.x = f2bf(p.x); o.y = f2bf(p.y); o.z = f2bf(p.z); o.w = f2bf(p.w);
            ((ushort4*)xb)[i] = o;
        } else {
            ((ushort4*)xb)[i] = ((const ushort4*)x)[i];
        }
    }
}

// ---- build fixed-cap adjacency-by-dst: cnt[dst]++, csr[dst*CAP+pos]=src ----
__global__ void k_fill(const int* __restrict__ ei, int* __restrict__ cnt,
                       int* __restrict__ csr, const int* __restrict__ flags) {
    int e = blockIdx.x * blockDim.x + threadIdx.x;
    if (e >= N_EDGES) return;
    int i64 = flags[1];
    int src = ei[e << i64], dst = ei[(N_EDGES + e) << i64];
    int pos = atomicAdd(&cnt[dst], 1);
    if (pos < CAP) csr[dst * CAP + pos] = src;
}

// ---- fused agg1 + GEMM1 + GEMM2: block = 4 waves = 32 nodes.
//  phase A: gather mean(x) into LDS (per-lane 2ch, 8-deep clamped loads, no reduce)
//  phase B: wave = out-quarter, MFMA -> h (relu) kept in the SAME LDS buffer
//  phase C: wave = t-quarter, MFMA h_lds @ W2 -> tb global ----
__global__ __launch_bounds__(256) void k_fused1(
    const int* __restrict__ cnt, const int* __restrict__ csr,
    const unsigned short* __restrict__ xb, const unsigned short* __restrict__ wts,
    unsigned short* __restrict__ tb)
{
    __shared__ unsigned short sm[32][136];  // 272B row stride; holds mean, then h
    int wave = threadIdx.x >> 6, lane = threadIdx.x & 63;
    int nb0 = blockIdx.x * 32;

    // ---------- phase A: wave handles 8 nodes, lane owns channels 2l,2l+1 ----------
    {
        int nA = nb0 + wave * 8;
        int half = lane >> 5, sl = lane & 31;
        int rows[4];
#pragma unroll
        for (int p = 0; p < 4; ++p)
            rows[p] = csr[(size_t)(nA + p * 2 + half) * CAP + sl];
        int dpre = (lane < 8) ? cnt[nA + lane] : 0;
        int c2 = lane << 1;

#pragma unroll
        for (int j = 0; j < 8; ++j) {
            int deg = __shfl(dpre, j);
            int m = deg < CAP ? deg : CAP;
            float s0 = 0.f, s1 = 0.f;
            for (int e0 = 0; e0 < m; e0 += 8) {
                unsigned int v[8];
#pragma unroll
                for (int u = 0; u < 8; ++u) {
                    int e = e0 + u;
                    int sidx = __shfl(rows[j >> 1], (j & 1) * 32 + e);
                    sidx = (e < m) ? sidx : 0;                   // clamp: always load
                    v[u] = *(const unsigned int*)(xb + (size_t)sidx * 128 + c2);
                }
#pragma unroll
                for (int u = 0; u < 8; ++u) {
                    unsigned int w = ((e0 + u) < m) ? v[u] : 0u; // single select
                    s0 += asf(w << 16);                          // lo bf16 -> f32
                    s1 += asf(w & 0xffff0000u);                  // hi bf16 -> f32
                }
            }
            float inv = 1.0f / (deg > 1 ? (float)deg : 1.0f);
            unsigned int o = (unsigned int)f2bf(s0 * inv) | ((unsigned int)f2bf(s1 * inv) << 16);
            *(unsigned int*)&sm[wave * 8 + j][c2] = o;
        }
    }
    __syncthreads();

    // ---------- phase B: h = relu(b1 + [mean||x] @ W1^T), result -> LDS ----------
    int qq = wave;                      // out-channel quarter: ch [qq*32, qq*32+32)
    int row = lane & 15, kq = lane >> 4;
    int col = lane & 15, rq = lane >> 4;
    f32x4 acc[2][2];                    // [tile][sub]
    {
        bf16x8 Wf[16];                  // 2 out-tiles x 8 k-steps (K=256)
#pragma unroll
        for (int t = 0; t < 2; ++t)
#pragma unroll
            for (int ks = 0; ks < 8; ++ks) {
                const int k0 = ks * 32;
                const unsigned short* base = wts + (k0 < 128 ? CW1L : CW1R)
                    + (size_t)(qq * 32 + t * 16 + row) * 128 + (k0 & 127) + kq * 8;
                Wf[t * 8 + ks] = *reinterpret_cast<const bf16x8*>(base);
            }
#pragma unroll
        for (int i = 0; i < 2; ++i) {
            bf16x8 Af[8];
#pragma unroll
            for (int ks = 0; ks < 4; ++ks)
                Af[ks] = *reinterpret_cast<const bf16x8*>(&sm[i * 16 + row][ks * 32 + kq * 8]);
            const unsigned short* rx = xb + (size_t)(nb0 + i * 16 + row) * 128 + kq * 8;
#pragma unroll
            for (int ks = 0; ks < 4; ++ks)
                Af[4 + ks] = *reinterpret_cast<const bf16x8*>(rx + ks * 32);
            acc[i][0] = (f32x4){0.f, 0.f, 0.f, 0.f};
            acc[i][1] = (f32x4){0.f, 0.f, 0.f, 0.f};
#pragma unroll
            for (int ks = 0; ks < 8; ++ks) {
                acc[i][0] = __builtin_amdgcn_mfma_f32_16x16x32_bf16(Af[ks], Wf[ks],     acc[i][0], 0, 0, 0);
                acc[i][1] = __builtin_amdgcn_mfma_f32_16x16x32_bf16(Af[ks], Wf[8 + ks], acc[i][1], 0, 0, 0);
            }
        }
    }
    __syncthreads();                    // all waves done reading mean from LDS
    {
        float bias0 = bf2f(wts[CB1 + qq * 32 + col]);
        float bias1 = bf2f(wts[CB1 + qq * 32 + 16 + col]);
#pragma unroll
        for (int i = 0; i < 2; ++i)
#pragma unroll
            for (int r = 0; r < 4; ++r) {
                int nl = i * 16 + rq * 4 + r;
                float v0 = acc[i][0][r] + bias0; v0 = v0 > 0.f ? v0 : 0.f;
                float v1 = acc[i][1][r] + bias1; v1 = v1 > 0.f ? v1 : 0.f;
                sm[nl][qq * 32 + col]      = f2bf(v0);
                sm[nl][qq * 32 + 16 + col] = f2bf(v1);
            }
    }
    __syncthreads();                    // h fully in LDS

    // ---------- phase C: t = h @ [W2l;W2r]^T -> tb ----------
    {
        const size_t wbase = (qq < 2) ? (CW2L + (size_t)(qq * 32) * 128)
                                      : (CW2R + (size_t)((qq - 2) * 32) * 128);
        bf16x8 Wg[8];                   // 2 out-tiles x 4 k-steps (K=128)
#pragma unroll
        for (int t = 0; t < 2; ++t)
#pragma unroll
            for (int ks = 0; ks < 4; ++ks)
                Wg[t * 4 + ks] = *reinterpret_cast<const bf16x8*>(
                    wts + wbase + (size_t)(t * 16 + row) * 128 + ks * 32 + kq * 8);
#pragma unroll
        for (int i = 0; i < 2; ++i) {
            bf16x8 Ag[4];
#pragma unroll
            for (int ks = 0; ks < 4; ++ks)
                Ag[ks] = *reinterpret_cast<const bf16x8*>(&sm[i * 16 + row][ks * 32 + kq * 8]);
            f32x4 c0 = (f32x4){0.f, 0.f, 0.f, 0.f};
            f32x4 c1 = (f32x4){0.f, 0.f, 0.f, 0.f};
#pragma unroll
            for (int ks = 0; ks < 4; ++ks) {
                c0 = __builtin_amdgcn_mfma_f32_16x16x32_bf16(Ag[ks], Wg[ks],     c0, 0, 0, 0);
                c1 = __builtin_amdgcn_mfma_f32_16x16x32_bf16(Ag[ks], Wg[4 + ks], c1, 0, 0, 0);
            }
#pragma unroll
            for (int r = 0; r < 4; ++r) {
                int n = nb0 + i * 16 + rq * 4 + r;
                tb[(size_t)n * 128 + qq * 32 + col]      = f2bf(c0[r]);
                tb[(size_t)n * 128 + qq * 32 + 16 + col] = f2bf(c1[r]);
            }
        }
    }
}

// ---- layer-2 gather + combine: z = agg(t_l)/deg + b2 + t_r -> bf16 zb.
//  2 nodes/wave (half-wave each), lane owns 2 ch, 8-deep clamped loads, no reduce ----
__global__ __launch_bounds__(256) void k_agg2c(
    const int* __restrict__ cnt, const int* __restrict__ csr,
    const unsigned short* __restrict__ tb, const unsigned short* __restrict__ wts,
    unsigned short* __restrict__ zb) {
    int wv = (int)((blockIdx.x * blockDim.x + threadIdx.x) >> 6);
    int n2 = wv * 2;
    if (n2 >= N_NODES) return;
    int lane = threadIdx.x & 63;
    int half = lane >> 5, sl = lane & 31;
    int n = n2 + half;                  // N_NODES even -> both halves valid
    int dpre = (lane < 2) ? cnt[n2 + lane] : 0;
    int deg = __shfl(dpre, half);
    int m = deg < CAP ? deg : CAP;
    int mo = __shfl(m, lane ^ 32);      // other half's m
    int mmax = m > mo ? m : mo;
    int srcrow = csr[(size_t)n * CAP + sl];
    int c2 = sl << 1;                   // channels 2sl, 2sl+1 of t_l
    float s0 = 0.f, s1 = 0.f;
    for (int e0 = 0; e0 < mmax; e0 += 8) {
        unsigned int v[8];
#pragma unroll
        for (int u = 0; u < 8; ++u) {
            int e = e0 + u;
            int sidx = __shfl(srcrow, half * 32 + e);
            sidx = (e < m) ? sidx : 0;
            v[u] = *(const unsigned int*)(tb + (size_t)sidx * 128 + c2);
        }
#pragma unroll
        for (int u = 0; u < 8; ++u) {
            unsigned int w = ((e0 + u) < m) ? v[u] : 0u;
            s0 += asf(w << 16);
            s1 += asf(w & 0xffff0000u);
        }
    }
    float inv = 1.0f / (deg > 1 ? (float)deg : 1.0f);
    unsigned int tr = *(const unsigned int*)(tb + (size_t)n * 128 + 64 + c2);
    unsigned int bb = *(const unsigned int*)(wts + CB2 + c2);
    float zx = s0 * inv + asf(bb << 16)          + asf(tr << 16);
    float zy = s1 * inv + asf(bb & 0xffff0000u)  + asf(tr & 0xffff0000u);
    unsigned int o = (unsigned int)f2bf(zx) | ((unsigned int)f2bf(zy) << 16);
    *(unsigned int*)(zb + (size_t)n * 64 + c2) = o;
}

// ---- decode: scores[e] = dot64(zb[a], zb[b]); 8 edges/wave, 8 lanes x uint4 (8ch) ----
__global__ void k_decode(const int* __restrict__ eli, const unsigned short* __restrict__ zb,
                         void* __restrict__ out, const int* __restrict__ flags) {
    long long t = (long long)blockIdx.x * blockDim.x + threadIdx.x;
    int e = (int)(t >> 3);
    if (e >= N_LABEL) return;
    int f32m = flags[0], i64 = flags[1];
    int q = threadIdx.x & 7;
    int a = eli[e << i64], b = eli[(N_LABEL + e) << i64];
    uint4 pa = *(const uint4*)(zb + (size_t)a * 64 + q * 8);
    uint4 pb = *(const uint4*)(zb + (size_t)b * 64 + q * 8);
    float s = asf(pa.x << 16) * asf(pb.x << 16) + asf(pa.x & 0xffff0000u) * asf(pb.x & 0xffff0000u)
            + asf(pa.y << 16) * asf(pb.y << 16) + asf(pa.y & 0xffff0000u) * asf(pb.y & 0xffff0000u)
            + asf(pa.z << 16) * asf(pb.z << 16) + asf(pa.z & 0xffff0000u) * asf(pb.z & 0xffff0000u)
            + asf(pa.w << 16) * asf(pb.w << 16) + asf(pa.w & 0xffff0000u) * asf(pb.w & 0xffff0000u);
#pragma unroll
    for (int off = 1; off < 8; off <<= 1) s += __shfl_xor(s, off);
    if (q == 0) {
        if (f32m) ((float*)out)[e] = s;
        else      ((unsigned short*)out)[e] = f2bf(s);
    }
}

extern "C" void kernel_launch(void* const* d_in, const int* in_sizes, int n_in,
                              void* d_out, int out_size, void* d_ws, size_t ws_size,
                              hipStream_t stream) {
    const void* x   = d_in[0];
    const int*  ei  = (const int*)d_in[1];
    const int*  eli = (const int*)d_in[2];
    const void* W1l = d_in[3];
    const void* b1  = d_in[4];
    const void* W1r = d_in[5];
    const void* W2l = d_in[6];
    const void* b2  = d_in[7];
    const void* W2r = d_in[8];

    char* ws = (char*)d_ws;
    const size_t offFlag = 0;
    const size_t offCnt  = 1024;                       // int[100000] -> 400 KB
    const size_t offWts  = 801024;                     // bf16[NWTS]  -> ~96 KB
    const size_t offCsr  = 1u << 20;                              // int[N*32]      12.8 MB
    const size_t offXb   = offCsr + (size_t)N_NODES * CAP * 4;    // xb bf16[N,128] 25.6 MB
    const size_t offTb   = offXb  + (size_t)N_NODES * 128 * 2;    // tb bf16[N,128] 25.6 MB
    const size_t offZb   = offTb  + (size_t)N_NODES * 128 * 2;    // zb bf16[N,64]  12.8 MB
    // total = 1 MB + 12.8 + 25.6 + 25.6 + 12.8 = 77.8 MB

    int*            flags = (int*)(ws + offFlag);
    int*            cnt   = (int*)(ws + offCnt);
    unsigned short* wts   = (unsigned short*)(ws + offWts);
    int*            csr   = (int*)(ws + offCsr);
    unsigned short* xb    = (unsigned short*)(ws + offXb);
    unsigned short* tb    = (unsigned short*)(ws + offTb);
    unsigned short* zb    = (unsigned short*)(ws + offZb);

    hipMemsetAsync(ws, 0, 1u << 20, stream);   // flags + cnt (wts rewritten anyway)

    k_detect<<<1, 64, 0, stream>>>((const unsigned int*)x, (const unsigned int*)ei, flags);

    // fused streaming canonicalize (weights + x)
    k_convwx<<<NB_W + NB_X, 256, 0, stream>>>(W1l, b1, W1r, W2l, b2, W2r, wts, x, xb, flags);

    k_fill<<<(N_EDGES + 255) / 256, 256, 0, stream>>>(ei, cnt, csr, flags);

    // fused agg1+gemm1+gemm2: 32 nodes/block, 100000/32 = 3125 blocks exactly
    k_fused1<<<N_NODES / 32, 256, 0, stream>>>(cnt, csr, xb, wts, tb);

    // agg2c: 2 nodes/wave -> 50000 waves -> 12500 blocks
    k_agg2c<<<12500, 256, 0, stream>>>(cnt, csr, tb, wts, zb);

    // decode: 8 edges/wave -> 100000*8 threads -> 3125 blocks
    k_decode<<<(N_LABEL * 8) / 256, 256, 0, stream>>>(eli, zb, d_out, flags);
}

// Round 10
// 232.603 us; speedup vs baseline: 1.2848x; 1.0003x over previous
//
#include <hip/hip_runtime.h>

#define N_NODES 100000
#define N_EDGES 640000
#define N_LABEL 100000
#define CAP 32   // max stored neighbors/node; deg ~Poisson(6.4) -> P(any>32) ~ 1e-9
// IN_C=128, HID_C=128, OUT_C=64

typedef __bf16 bf16x8 __attribute__((ext_vector_type(8)));
typedef float f32x4 __attribute__((ext_vector_type(4)));

// canonical bf16 weight offsets (in shorts) inside ws weight region
#define CW1L 0
#define CB1  16384
#define CW1R 16512
#define CW2L 32896
#define CB2  41088
#define CW2R 41152
#define NWTS 49344

// fused convw|convx block split (both pure streaming); x-path: 2 ushort4 groups/thread
#define NB_W 193
#define NB_X 6250

__device__ __forceinline__ float bf2f(unsigned short u) {
    union { unsigned int i; float f; } c; c.i = ((unsigned int)u) << 16; return c.f;
}
__device__ __forceinline__ float asf(unsigned int u) {
    union { unsigned int i; float f; } c; c.i = u; return c.f;
}
__device__ __forceinline__ unsigned short f2bf(float f) {
    union { float f; unsigned int i; } c; c.f = f;
    unsigned int lsb = (c.i >> 16) & 1u;
    c.i += 0x7fffu + lsb;              // round-to-nearest-even
    return (unsigned short)(c.i >> 16);
}

// ---- init: zero cnt; block 0 wave 0 additionally detects dtypes ----
//  flags[0]=1 if x is f32 storage; flags[1]=1 if edges are int64
__global__ void k_init(const unsigned int* __restrict__ xw,
                       const unsigned int* __restrict__ eiw,
                       int* __restrict__ flags, int* __restrict__ cnt) {
    int i = blockIdx.x * blockDim.x + threadIdx.x;
    if (i < N_NODES) cnt[i] = 0;
    if (blockIdx.x == 0 && threadIdx.x < 64) {   // wave 0 exactly
        int l = threadIdx.x;
        unsigned int w = xw[l];
        unsigned short lo = (unsigned short)(w & 0xffffu);
        int e = (lo >> 7) & 0xff;
        bool bf_like = (lo == 0) || (e >= 98 && e <= 138);
        unsigned long long m = __ballot(bf_like);
        unsigned int ew = eiw[2 * l + 1];
        unsigned long long mz = __ballot(ew == 0u);
        if (l == 0) {
            flags[0] = (__popcll(m) < 48) ? 1 : 0;
            flags[1] = (__popcll(mz) == 64) ? 1 : 0;
        }
    }
}

// ---- fused streaming canonicalize: weights -> bf16 wts | x -> bf16 xb (2 groups/thr) ----
__global__ void k_convwx(const void* W1l, const void* b1, const void* W1r,
                         const void* W2l, const void* b2, const void* W2r,
                         unsigned short* __restrict__ wts,
                         const void* __restrict__ x, unsigned short* __restrict__ xb,
                         const int* __restrict__ flags) {
    int b = blockIdx.x;
    int f32m = flags[0];
    if (b < NB_W) {
        int i = b * 256 + threadIdx.x;
        if (i >= NWTS) return;
        const void* src; int local;
        if      (i < CB1)  { src = W1l; local = i; }
        else if (i < CW1R) { src = b1;  local = i - CB1; }
        else if (i < CW2L) { src = W1r; local = i - CW1R; }
        else if (i < CB2)  { src = W2l; local = i - CW2L; }
        else if (i < CW2R) { src = b2;  local = i - CB2; }
        else               { src = W2r; local = i - CW2R; }
        wts[i] = f32m ? f2bf(((const float*)src)[local]) : ((const unsigned short*)src)[local];
    } else {
        int base = (b - NB_W) * 512 + threadIdx.x;
#pragma unroll
        for (int g = 0; g < 2; ++g) {
            int i = base + g * 256;                 // coalesced pair of group-indices
            if (i >= N_NODES * 32) continue;        // 12.8M elems / 4
            if (f32m) {
                float4 p = ((const float4*)x)[i];
                ushort4 o;
                o.x = f2bf(p.x); o.y = f2bf(p.y); o.z = f2bf(p.z); o.w = f2bf(p.w);
                ((ushort4*)xb)[i] = o;
            } else {
                ((ushort4*)xb)[i] = ((const ushort4*)x)[i];
            }
        }
    }
}

// ---- build fixed-cap adjacency-by-dst: cnt[dst]++, csr[dst*CAP+pos]=src ----
__global__ void k_fill(const int* __restrict__ ei, int* __restrict__ cnt,
                       int* __restrict__ csr, const int* __restrict__ flags) {
    int e = blockIdx.x * blockDim.x + threadIdx.x;
    if (e >= N_EDGES) return;
    int i64 = flags[1];
    int src = ei[e << i64], dst = ei[(N_EDGES + e) << i64];
    int pos = atomicAdd(&cnt[dst], 1);
    if (pos < CAP) csr[dst * CAP + pos] = src;
}

// ---- fused agg1 + GEMM1 + GEMM2: block = 4 waves = 32 nodes.
//  phase A: gather mean(x) into LDS (per-lane 2ch, 8-deep clamped loads, no reduce)
//  phase B: wave = out-quarter, MFMA -> h (relu) kept in the SAME LDS buffer
//  phase C: wave = t-quarter, MFMA h_lds @ W2 -> tbl/tbr global ----
__global__ __launch_bounds__(256) void k_fused1(
    const int* __restrict__ cnt, const int* __restrict__ csr,
    const unsigned short* __restrict__ xb, const unsigned short* __restrict__ wts,
    unsigned short* __restrict__ tbl, unsigned short* __restrict__ tbr)
{
    __shared__ unsigned short sm[32][136];  // 272B row stride; holds mean, then h
    int wave = threadIdx.x >> 6, lane = threadIdx.x & 63;
    int nb0 = blockIdx.x * 32;

    // ---------- phase A: wave handles 8 nodes, lane owns channels 2l,2l+1 ----------
    {
        int nA = nb0 + wave * 8;
        int half = lane >> 5, sl = lane & 31;
        int rows[4];
#pragma unroll
        for (int p = 0; p < 4; ++p)
            rows[p] = csr[(size_t)(nA + p * 2 + half) * CAP + sl];
        int dpre = (lane < 8) ? cnt[nA + lane] : 0;
        int c2 = lane << 1;

#pragma unroll
        for (int j = 0; j < 8; ++j) {
            int deg = __shfl(dpre, j);
            int m = deg < CAP ? deg : CAP;
            float s0 = 0.f, s1 = 0.f;
            for (int e0 = 0; e0 < m; e0 += 8) {
                unsigned int v[8];
#pragma unroll
                for (int u = 0; u < 8; ++u) {
                    int e = e0 + u;
                    int sidx = __shfl(rows[j >> 1], (j & 1) * 32 + e);
                    sidx = (e < m) ? sidx : 0;                   // clamp: always load
                    v[u] = *(const unsigned int*)(xb + (size_t)sidx * 128 + c2);
                }
#pragma unroll
                for (int u = 0; u < 8; ++u) {
                    unsigned int w = ((e0 + u) < m) ? v[u] : 0u; // single select
                    s0 += asf(w << 16);                          // lo bf16 -> f32
                    s1 += asf(w & 0xffff0000u);                  // hi bf16 -> f32
                }
            }
            float inv = 1.0f / (deg > 1 ? (float)deg : 1.0f);
            unsigned int o = (unsigned int)f2bf(s0 * inv) | ((unsigned int)f2bf(s1 * inv) << 16);
            *(unsigned int*)&sm[wave * 8 + j][c2] = o;
        }
    }
    __syncthreads();

    // ---------- phase B: h = relu(b1 + [mean||x] @ W1^T), result -> LDS ----------
    int qq = wave;                      // out-channel quarter: ch [qq*32, qq*32+32)
    int row = lane & 15, kq = lane >> 4;
    int col = lane & 15, rq = lane >> 4;
    f32x4 acc[2][2];                    // [tile][sub]
    {
        bf16x8 Wf[16];                  // 2 out-tiles x 8 k-steps (K=256)
#pragma unroll
        for (int t = 0; t < 2; ++t)
#pragma unroll
            for (int ks = 0; ks < 8; ++ks) {
                const int k0 = ks * 32;
                const unsigned short* base = wts + (k0 < 128 ? CW1L : CW1R)
                    + (size_t)(qq * 32 + t * 16 + row) * 128 + (k0 & 127) + kq * 8;
                Wf[t * 8 + ks] = *reinterpret_cast<const bf16x8*>(base);
            }
#pragma unroll
        for (int i = 0; i < 2; ++i) {
            bf16x8 Af[8];
#pragma unroll
            for (int ks = 0; ks < 4; ++ks)
                Af[ks] = *reinterpret_cast<const bf16x8*>(&sm[i * 16 + row][ks * 32 + kq * 8]);
            const unsigned short* rx = xb + (size_t)(nb0 + i * 16 + row) * 128 + kq * 8;
#pragma unroll
            for (int ks = 0; ks < 4; ++ks)
                Af[4 + ks] = *reinterpret_cast<const bf16x8*>(rx + ks * 32);
            acc[i][0] = (f32x4){0.f, 0.f, 0.f, 0.f};
            acc[i][1] = (f32x4){0.f, 0.f, 0.f, 0.f};
#pragma unroll
            for (int ks = 0; ks < 8; ++ks) {
                acc[i][0] = __builtin_amdgcn_mfma_f32_16x16x32_bf16(Af[ks], Wf[ks],     acc[i][0], 0, 0, 0);
                acc[i][1] = __builtin_amdgcn_mfma_f32_16x16x32_bf16(Af[ks], Wf[8 + ks], acc[i][1], 0, 0, 0);
            }
        }
    }
    __syncthreads();                    // all waves done reading mean from LDS
    {
        float bias0 = bf2f(wts[CB1 + qq * 32 + col]);
        float bias1 = bf2f(wts[CB1 + qq * 32 + 16 + col]);
#pragma unroll
        for (int i = 0; i < 2; ++i)
#pragma unroll
            for (int r = 0; r < 4; ++r) {
                int nl = i * 16 + rq * 4 + r;
                float v0 = acc[i][0][r] + bias0; v0 = v0 > 0.f ? v0 : 0.f;
                float v1 = acc[i][1][r] + bias1; v1 = v1 > 0.f ? v1 : 0.f;
                sm[nl][qq * 32 + col]      = f2bf(v0);
                sm[nl][qq * 32 + 16 + col] = f2bf(v1);
            }
    }
    __syncthreads();                    // h fully in LDS

    // ---------- phase C: t = h @ [W2l;W2r]^T -> tbl (qq<2) / tbr (qq>=2) ----------
    {
        const size_t wbase = (qq < 2) ? (CW2L + (size_t)(qq * 32) * 128)
                                      : (CW2R + (size_t)((qq - 2) * 32) * 128);
        bf16x8 Wg[8];                   // 2 out-tiles x 4 k-steps (K=128)
#pragma unroll
        for (int t = 0; t < 2; ++t)
#pragma unroll
            for (int ks = 0; ks < 4; ++ks)
                Wg[t * 4 + ks] = *reinterpret_cast<const bf16x8*>(
                    wts + wbase + (size_t)(t * 16 + row) * 128 + ks * 32 + kq * 8);
        unsigned short* dst = (qq < 2) ? tbl : tbr;
        int cb = (qq & 1) * 32;
#pragma unroll
        for (int i = 0; i < 2; ++i) {
            bf16x8 Ag[4];
#pragma unroll
            for (int ks = 0; ks < 4; ++ks)
                Ag[ks] = *reinterpret_cast<const bf16x8*>(&sm[i * 16 + row][ks * 32 + kq * 8]);
            f32x4 c0 = (f32x4){0.f, 0.f, 0.f, 0.f};
            f32x4 c1 = (f32x4){0.f, 0.f, 0.f, 0.f};
#pragma unroll
            for (int ks = 0; ks < 4; ++ks) {
                c0 = __builtin_amdgcn_mfma_f32_16x16x32_bf16(Ag[ks], Wg[ks],     c0, 0, 0, 0);
                c1 = __builtin_amdgcn_mfma_f32_16x16x32_bf16(Ag[ks], Wg[4 + ks], c1, 0, 0, 0);
            }
#pragma unroll
            for (int r = 0; r < 4; ++r) {
                int n = nb0 + i * 16 + rq * 4 + r;
                dst[(size_t)n * 64 + cb + col]      = f2bf(c0[r]);
                dst[(size_t)n * 64 + cb + 16 + col] = f2bf(c1[r]);
            }
        }
    }
}

// ---- layer-2 gather + combine: z = agg(tbl)/deg + b2 + tbr -> bf16 zb.
//  2 nodes/wave (half-wave each), lane owns 2 ch, 8-deep clamped loads, no reduce ----
__global__ __launch_bounds__(256) void k_agg2c(
    const int* __restrict__ cnt, const int* __restrict__ csr,
    const unsigned short* __restrict__ tbl, const unsigned short* __restrict__ tbr,
    const unsigned short* __restrict__ wts, unsigned short* __restrict__ zb) {
    int wv = (int)((blockIdx.x * blockDim.x + threadIdx.x) >> 6);
    int n2 = wv * 2;
    if (n2 >= N_NODES) return;
    int lane = threadIdx.x & 63;
    int half = lane >> 5, sl = lane & 31;
    int n = n2 + half;                  // N_NODES even -> both halves valid
    int dpre = (lane < 2) ? cnt[n2 + lane] : 0;
    int deg = __shfl(dpre, half);
    int m = deg < CAP ? deg : CAP;
    int mo = __shfl(m, lane ^ 32);      // other half's m
    int mmax = m > mo ? m : mo;
    int srcrow = csr[(size_t)n * CAP + sl];
    int c2 = sl << 1;                   // channels 2sl, 2sl+1 of t_l
    float s0 = 0.f, s1 = 0.f;
    for (int e0 = 0; e0 < mmax; e0 += 8) {
        unsigned int v[8];
#pragma unroll
        for (int u = 0; u < 8; ++u) {
            int e = e0 + u;
            int sidx = __shfl(srcrow, half * 32 + e);
            sidx = (e < m) ? sidx : 0;
            v[u] = *(const unsigned int*)(tbl + (size_t)sidx * 64 + c2);
        }
#pragma unroll
        for (int u = 0; u < 8; ++u) {
            unsigned int w = ((e0 + u) < m) ? v[u] : 0u;
            s0 += asf(w << 16);
            s1 += asf(w & 0xffff0000u);
        }
    }
    float inv = 1.0f / (deg > 1 ? (float)deg : 1.0f);
    unsigned int tr = *(const unsigned int*)(tbr + (size_t)n * 64 + c2);
    unsigned int bb = *(const unsigned int*)(wts + CB2 + c2);
    float zx = s0 * inv + asf(bb << 16)          + asf(tr << 16);
    float zy = s1 * inv + asf(bb & 0xffff0000u)  + asf(tr & 0xffff0000u);
    unsigned int o = (unsigned int)f2bf(zx) | ((unsigned int)f2bf(zy) << 16);
    *(unsigned int*)(zb + (size_t)n * 64 + c2) = o;
}

// ---- decode: scores[e] = dot64(zb[a], zb[b]); 8 edges/wave, 8 lanes x uint4 (8ch) ----
__global__ void k_decode(const int* __restrict__ eli, const unsigned short* __restrict__ zb,
                         void* __restrict__ out, const int* __restrict__ flags) {
    long long t = (long long)blockIdx.x * blockDim.x + threadIdx.x;
    int e = (int)(t >> 3);
    if (e >= N_LABEL) return;
    int f32m = flags[0], i64 = flags[1];
    int q = threadIdx.x & 7;
    int a = eli[e << i64], b = eli[(N_LABEL + e) << i64];
    uint4 pa = *(const uint4*)(zb + (size_t)a * 64 + q * 8);
    uint4 pb = *(const uint4*)(zb + (size_t)b * 64 + q * 8);
    float s = asf(pa.x << 16) * asf(pb.x << 16) + asf(pa.x & 0xffff0000u) * asf(pb.x & 0xffff0000u)
            + asf(pa.y << 16) * asf(pb.y << 16) + asf(pa.y & 0xffff0000u) * asf(pb.y & 0xffff0000u)
            + asf(pa.z << 16) * asf(pb.z << 16) + asf(pa.z & 0xffff0000u) * asf(pb.z & 0xffff0000u)
            + asf(pa.w << 16) * asf(pb.w << 16) + asf(pa.w & 0xffff0000u) * asf(pb.w & 0xffff0000u);
#pragma unroll
    for (int off = 1; off < 8; off <<= 1) s += __shfl_xor(s, off);
    if (q == 0) {
        if (f32m) ((float*)out)[e] = s;
        else      ((unsigned short*)out)[e] = f2bf(s);
    }
}

extern "C" void kernel_launch(void* const* d_in, const int* in_sizes, int n_in,
                              void* d_out, int out_size, void* d_ws, size_t ws_size,
                              hipStream_t stream) {
    const void* x   = d_in[0];
    const int*  ei  = (const int*)d_in[1];
    const int*  eli = (const int*)d_in[2];
    const void* W1l = d_in[3];
    const void* b1  = d_in[4];
    const void* W1r = d_in[5];
    const void* W2l = d_in[6];
    const void* b2  = d_in[7];
    const void* W2r = d_in[8];

    char* ws = (char*)d_ws;
    const size_t offFlag = 0;
    const size_t offCnt  = 1024;                       // int[100000] -> 400 KB
    const size_t offWts  = 801024;                     // bf16[NWTS]  -> ~96 KB
    const size_t offCsr  = 1u << 20;                              // int[N*32]       12.8 MB
    const size_t offXb   = offCsr + (size_t)N_NODES * CAP * 4;    // xb  bf16[N,128] 25.6 MB
    const size_t offTbl  = offXb  + (size_t)N_NODES * 128 * 2;    // tbl bf16[N,64]  12.8 MB
    const size_t offTbr  = offTbl + (size_t)N_NODES * 64 * 2;     // tbr bf16[N,64]  12.8 MB
    const size_t offZb   = offTbr + (size_t)N_NODES * 64 * 2;     // zb  bf16[N,64]  12.8 MB
    // total = 1 MB + 12.8 + 25.6 + 12.8 + 12.8 + 12.8 = 77.8 MB (same proven footprint)

    int*            flags = (int*)(ws + offFlag);
    int*            cnt   = (int*)(ws + offCnt);
    unsigned short* wts   = (unsigned short*)(ws + offWts);
    int*            csr   = (int*)(ws + offCsr);
    unsigned short* xb    = (unsigned short*)(ws + offXb);
    unsigned short* tbl   = (unsigned short*)(ws + offTbl);
    unsigned short* tbr   = (unsigned short*)(ws + offTbr);
    unsigned short* zb    = (unsigned short*)(ws + offZb);

    // init: zero cnt + detect dtypes (no memset dispatch; csr needs no zeroing — clamped)
    k_init<<<(N_NODES + 255) / 256, 256, 0, stream>>>((const unsigned int*)x,
                                                      (const unsigned int*)ei, flags, cnt);

    // fused streaming canonicalize (weights + x)
    k_convwx<<<NB_W + NB_X, 256, 0, stream>>>(W1l, b1, W1r, W2l, b2, W2r, wts, x, xb, flags);

    k_fill<<<(N_EDGES + 255) / 256, 256, 0, stream>>>(ei, cnt, csr, flags);

    // fused agg1+gemm1+gemm2: 32 nodes/block, 100000/32 = 3125 blocks exactly
    k_fused1<<<N_NODES / 32, 256, 0, stream>>>(cnt, csr, xb, wts, tbl, tbr);

    // agg2c: 2 nodes/wave -> 50000 waves -> 12500 blocks
    k_agg2c<<<12500, 256, 0, stream>>>(cnt, csr, tbl, tbr, wts, zb);

    // decode: 8 edges/wave -> 100000*8 threads -> 3125 blocks
    k_decode<<<(N_LABEL * 8) / 256, 256, 0, stream>>>(eli, zb, d_out, flags);
}

// Round 12
// 227.032 us; speedup vs baseline: 1.3164x; 1.0245x over previous
//
#include <hip/hip_runtime.h>

#define N_NODES 100000
#define N_EDGES 640000
#define N_LABEL 100000
#define CAP 32   // max stored neighbors/node; deg ~Poisson(6.4) -> P(any>32) ~ 1e-9
// IN_C=128, HID_C=128, OUT_C=64

typedef __bf16 bf16x8 __attribute__((ext_vector_type(8)));
typedef float f32x4 __attribute__((ext_vector_type(4)));

// canonical bf16 weight offsets (in shorts) inside ws weight region
#define CW1L 0
#define CB1  16384
#define CW1R 16512
#define CW2L 32896
#define CB2  41088
#define CW2R 41152
#define NWTS 49344

// k_prep block split: cnt-zero | weights | x-convert (all streaming)
#define NB_C 391
#define NB_W 193
#define NB_X 6250

__device__ __forceinline__ float bf2f(unsigned short u) {
    union { unsigned int i; float f; } c; c.i = ((unsigned int)u) << 16; return c.f;
}
__device__ __forceinline__ float asf(unsigned int u) {
    union { unsigned int i; float f; } c; c.i = u; return c.f;
}
__device__ __forceinline__ unsigned short f2bf(float f) {
    union { float f; unsigned int i; } c; c.f = f;
    unsigned int lsb = (c.i >> 16) & 1u;
    c.i += 0x7fffu + lsb;              // round-to-nearest-even
    return (unsigned short)(c.i >> 16);
}

// ---- per-wave dtype self-detection (deterministic; L1/L2-hot after first wave) ----
__device__ __forceinline__ void detect(const void* x, const int* ei, int& f32m, int& i64) {
    int lane = threadIdx.x & 63;
    unsigned int w = ((const unsigned int*)x)[lane];
    unsigned short lo = (unsigned short)(w & 0xffffu);
    int e = (lo >> 7) & 0xff;
    bool bf_like = (lo == 0) || (e >= 98 && e <= 138);
    f32m = (__popcll(__ballot(bf_like)) < 48) ? 1 : 0;
    unsigned int ew = ((const unsigned int*)ei)[2 * lane + 1];
    i64 = (__popcll(__ballot(ew == 0u)) == 64) ? 1 : 0;
}

// ---- prep: cnt zero | weights -> bf16 wts | x -> bf16 xb (2 groups/thr) ----
__global__ void k_prep(const void* W1l, const void* b1, const void* W1r,
                       const void* W2l, const void* b2, const void* W2r,
                       unsigned short* __restrict__ wts,
                       const void* __restrict__ x, unsigned short* __restrict__ xb,
                       const int* __restrict__ ei, int* __restrict__ cnt) {
    int b = blockIdx.x;
    if (b < NB_C) {
        int i = b * 256 + threadIdx.x;
        if (i < N_NODES) cnt[i] = 0;
        return;
    }
    int f32m, i64;
    detect(x, ei, f32m, i64);
    if (b < NB_C + NB_W) {
        int i = (b - NB_C) * 256 + threadIdx.x;
        if (i >= NWTS) return;
        const void* src; int local;
        if      (i < CB1)  { src = W1l; local = i; }
        else if (i < CW1R) { src = b1;  local = i - CB1; }
        else if (i < CW2L) { src = W1r; local = i - CW1R; }
        else if (i < CB2)  { src = W2l; local = i - CW2L; }
        else if (i < CW2R) { src = b2;  local = i - CB2; }
        else               { src = W2r; local = i - CW2R; }
        wts[i] = f32m ? f2bf(((const float*)src)[local]) : ((const unsigned short*)src)[local];
    } else {
        int base = (b - NB_C - NB_W) * 512 + threadIdx.x;
#pragma unroll
        for (int g = 0; g < 2; ++g) {
            int i = base + g * 256;
            if (i >= N_NODES * 32) continue;        // 12.8M elems / 4
            if (f32m) {
                float4 p = ((const float4*)x)[i];
                ushort4 o;
                o.x = f2bf(p.x); o.y = f2bf(p.y); o.z = f2bf(p.z); o.w = f2bf(p.w);
                ((ushort4*)xb)[i] = o;
            } else {
                ((ushort4*)xb)[i] = ((const ushort4*)x)[i];
            }
        }
    }
}

// ---- build fixed-cap adjacency-by-dst: cnt[dst]++, csr[dst*CAP+pos]=src ----
__global__ void k_fill(const int* __restrict__ ei, int* __restrict__ cnt,
                       int* __restrict__ csr, const void* __restrict__ x) {
    int f32m, i64;
    detect(x, ei, f32m, i64);
    int e = blockIdx.x * blockDim.x + threadIdx.x;
    if (e >= N_EDGES) return;
    int src = ei[e << i64], dst = ei[(N_EDGES + e) << i64];
    int pos = atomicAdd(&cnt[dst], 1);
    if (pos < CAP) csr[dst * CAP + pos] = src;
}

// ---- fused agg1 + GEMM1 + GEMM2: block = 4 waves = 32 nodes. ----
__global__ __launch_bounds__(256) void k_fused1(
    const int* __restrict__ cnt, const int* __restrict__ csr,
    const unsigned short* __restrict__ xb, const unsigned short* __restrict__ wts,
    unsigned short* __restrict__ tbl, unsigned short* __restrict__ tbr)
{
    __shared__ unsigned short sm[32][136];  // 272B row stride; holds mean, then h
    int wave = threadIdx.x >> 6, lane = threadIdx.x & 63;
    int nb0 = blockIdx.x * 32;

    // ---------- phase A: wave handles 8 nodes, lane owns channels 2l,2l+1 ----------
    {
        int nA = nb0 + wave * 8;
        int half = lane >> 5, sl = lane & 31;
        int rows[4];
#pragma unroll
        for (int p = 0; p < 4; ++p)
            rows[p] = csr[(size_t)(nA + p * 2 + half) * CAP + sl];
        int dpre = (lane < 8) ? cnt[nA + lane] : 0;
        int c2 = lane << 1;
#pragma unroll
        for (int j = 0; j < 8; ++j) {
            int deg = __shfl(dpre, j);
            int m = deg < CAP ? deg : CAP;
            float s0 = 0.f, s1 = 0.f;
            for (int e0 = 0; e0 < m; e0 += 8) {
                unsigned int v[8];
#pragma unroll
                for (int u = 0; u < 8; ++u) {
                    int e = e0 + u;
                    int sidx = __shfl(rows[j >> 1], (j & 1) * 32 + e);
                    sidx = (e < m) ? sidx : 0;                   // clamp: always load
                    v[u] = *(const unsigned int*)(xb + (size_t)sidx * 128 + c2);
                }
#pragma unroll
                for (int u = 0; u < 8; ++u) {
                    unsigned int w = ((e0 + u) < m) ? v[u] : 0u; // single select
                    s0 += asf(w << 16);
                    s1 += asf(w & 0xffff0000u);
                }
            }
            float inv = 1.0f / (deg > 1 ? (float)deg : 1.0f);
            unsigned int o = (unsigned int)f2bf(s0 * inv) | ((unsigned int)f2bf(s1 * inv) << 16);
            *(unsigned int*)&sm[wave * 8 + j][c2] = o;
        }
    }
    __syncthreads();

    // ---------- phase B: h = relu(b1 + [mean||x] @ W1^T) -> LDS ----------
    int qq = wave;
    int row = lane & 15, kq = lane >> 4;
    int col = lane & 15, rq = lane >> 4;
    f32x4 acc[2][2];
    {
        bf16x8 Wf[16];
#pragma unroll
        for (int t = 0; t < 2; ++t)
#pragma unroll
            for (int ks = 0; ks < 8; ++ks) {
                const int k0 = ks * 32;
                const unsigned short* base = wts + (k0 < 128 ? CW1L : CW1R)
                    + (size_t)(qq * 32 + t * 16 + row) * 128 + (k0 & 127) + kq * 8;
                Wf[t * 8 + ks] = *reinterpret_cast<const bf16x8*>(base);
            }
#pragma unroll
        for (int i = 0; i < 2; ++i) {
            bf16x8 Af[8];
#pragma unroll
            for (int ks = 0; ks < 4; ++ks)
                Af[ks] = *reinterpret_cast<const bf16x8*>(&sm[i * 16 + row][ks * 32 + kq * 8]);
            const unsigned short* rx = xb + (size_t)(nb0 + i * 16 + row) * 128 + kq * 8;
#pragma unroll
            for (int ks = 0; ks < 4; ++ks)
                Af[4 + ks] = *reinterpret_cast<const bf16x8*>(rx + ks * 32);
            acc[i][0] = (f32x4){0.f, 0.f, 0.f, 0.f};
            acc[i][1] = (f32x4){0.f, 0.f, 0.f, 0.f};
#pragma unroll
            for (int ks = 0; ks < 8; ++ks) {
                acc[i][0] = __builtin_amdgcn_mfma_f32_16x16x32_bf16(Af[ks], Wf[ks],     acc[i][0], 0, 0, 0);
                acc[i][1] = __builtin_amdgcn_mfma_f32_16x16x32_bf16(Af[ks], Wf[8 + ks], acc[i][1], 0, 0, 0);
            }
        }
    }
    __syncthreads();
    {
        float bias0 = bf2f(wts[CB1 + qq * 32 + col]);
        float bias1 = bf2f(wts[CB1 + qq * 32 + 16 + col]);
#pragma unroll
        for (int i = 0; i < 2; ++i)
#pragma unroll
            for (int r = 0; r < 4; ++r) {
                int nl = i * 16 + rq * 4 + r;
                float v0 = acc[i][0][r] + bias0; v0 = v0 > 0.f ? v0 : 0.f;
                float v1 = acc[i][1][r] + bias1; v1 = v1 > 0.f ? v1 : 0.f;
                sm[nl][qq * 32 + col]      = f2bf(v0);
                sm[nl][qq * 32 + 16 + col] = f2bf(v1);
            }
    }
    __syncthreads();

    // ---------- phase C: t = h @ [W2l;W2r]^T -> tbl (qq<2) / tbr (qq>=2) ----------
    {
        const size_t wbase = (qq < 2) ? (CW2L + (size_t)(qq * 32) * 128)
                                      : (CW2R + (size_t)((qq - 2) * 32) * 128);
        bf16x8 Wg[8];
#pragma unroll
        for (int t = 0; t < 2; ++t)
#pragma unroll
            for (int ks = 0; ks < 4; ++ks)
                Wg[t * 4 + ks] = *reinterpret_cast<const bf16x8*>(
                    wts + wbase + (size_t)(t * 16 + row) * 128 + ks * 32 + kq * 8);
        unsigned short* dst = (qq < 2) ? tbl : tbr;
        int cb = (qq & 1) * 32;
#pragma unroll
        for (int i = 0; i < 2; ++i) {
            bf16x8 Ag[4];
#pragma unroll
            for (int ks = 0; ks < 4; ++ks)
                Ag[ks] = *reinterpret_cast<const bf16x8*>(&sm[i * 16 + row][ks * 32 + kq * 8]);
            f32x4 c0 = (f32x4){0.f, 0.f, 0.f, 0.f};
            f32x4 c1 = (f32x4){0.f, 0.f, 0.f, 0.f};
#pragma unroll
            for (int ks = 0; ks < 4; ++ks) {
                c0 = __builtin_amdgcn_mfma_f32_16x16x32_bf16(Ag[ks], Wg[ks],     c0, 0, 0, 0);
                c1 = __builtin_amdgcn_mfma_f32_16x16x32_bf16(Ag[ks], Wg[4 + ks], c1, 0, 0, 0);
            }
#pragma unroll
            for (int r = 0; r < 4; ++r) {
                int n = nb0 + i * 16 + rq * 4 + r;
                dst[(size_t)n * 64 + cb + col]      = f2bf(c0[r]);
                dst[(size_t)n * 64 + cb + 16 + col] = f2bf(c1[r]);
            }
        }
    }
}

// ---- layer-2 gather + combine: z = agg(tbl)/deg + b2 + tbr -> bf16 zb.
//  4 nodes/wave (16-lane groups), lane owns 4 ch (uint2), 8-deep clamped loads ----
__global__ __launch_bounds__(256) void k_agg2c(
    const int* __restrict__ cnt, const int* __restrict__ csr,
    const unsigned short* __restrict__ tbl, const unsigned short* __restrict__ tbr,
    const unsigned short* __restrict__ wts, unsigned short* __restrict__ zb) {
    int wv = (int)((blockIdx.x * blockDim.x + threadIdx.x) >> 6);
    int n4 = wv * 4;
    if (n4 >= N_NODES) return;
    int lane = threadIdx.x & 63;
    int g16 = lane >> 4, sl = lane & 15;
    int n = n4 + g16;                   // N_NODES % 4 == 0 -> all groups valid
    int dpre = (lane < 4) ? cnt[n4 + lane] : 0;
    int deg = __shfl(dpre, g16);
    int m = deg < CAP ? deg : CAP;
    int srcA = csr[(size_t)n * CAP + sl];        // row elems 0..15 in group lanes
    int srcB = csr[(size_t)n * CAP + 16 + sl];   // row elems 16..31
    int c4 = sl << 2;                   // channels 4sl..4sl+3 of t_l
    float s0 = 0.f, s1 = 0.f, s2 = 0.f, s3 = 0.f;
    for (int e0 = 0; e0 < m; e0 += 8) {
        uint2 v[8];
#pragma unroll
        for (int u = 0; u < 8; ++u) {
            int e = e0 + u;
            int ia = __shfl(srcA, g16 * 16 + (e & 15));
            int ib = __shfl(srcB, g16 * 16 + (e & 15));
            int sidx = (e < 16) ? ia : ib;
            sidx = (e < m) ? sidx : 0;  // clamp: always load
            v[u] = *(const uint2*)(tbl + (size_t)sidx * 64 + c4);
        }
#pragma unroll
        for (int u = 0; u < 8; ++u) {
            bool ok = (e0 + u) < m;
            unsigned int wx = ok ? v[u].x : 0u;
            unsigned int wy = ok ? v[u].y : 0u;
            s0 += asf(wx << 16);
            s1 += asf(wx & 0xffff0000u);
            s2 += asf(wy << 16);
            s3 += asf(wy & 0xffff0000u);
        }
    }
    float inv = 1.0f / (deg > 1 ? (float)deg : 1.0f);
    uint2 tr = *(const uint2*)(tbr + (size_t)n * 64 + c4);
    uint2 bb = *(const uint2*)(wts + CB2 + c4);
    float z0 = s0 * inv + asf(bb.x << 16)         + asf(tr.x << 16);
    float z1 = s1 * inv + asf(bb.x & 0xffff0000u) + asf(tr.x & 0xffff0000u);
    float z2 = s2 * inv + asf(bb.y << 16)         + asf(tr.y << 16);
    float z3 = s3 * inv + asf(bb.y & 0xffff0000u) + asf(tr.y & 0xffff0000u);
    uint2 o;
    o.x = (unsigned int)f2bf(z0) | ((unsigned int)f2bf(z1) << 16);
    o.y = (unsigned int)f2bf(z2) | ((unsigned int)f2bf(z3) << 16);
    *(uint2*)(zb + (size_t)n * 64 + c4) = o;
}

// ---- decode: scores[e] = dot64(zb[a], zb[b]); 8 edges/wave, 8 lanes x uint4 (8ch) ----
__global__ void k_decode(const int* __restrict__ eli, const unsigned short* __restrict__ zb,
                         void* __restrict__ out, const void* __restrict__ x,
                         const int* __restrict__ ei) {
    int f32m, i64;
    detect(x, ei, f32m, i64);
    long long t = (long long)blockIdx.x * blockDim.x + threadIdx.x;
    int e = (int)(t >> 3);
    if (e >= N_LABEL) return;
    int q = threadIdx.x & 7;
    int a = eli[e << i64], b = eli[(N_LABEL + e) << i64];
    uint4 pa = *(const uint4*)(zb + (size_t)a * 64 + q * 8);
    uint4 pb = *(const uint4*)(zb + (size_t)b * 64 + q * 8);
    float s = asf(pa.x << 16) * asf(pb.x << 16) + asf(pa.x & 0xffff0000u) * asf(pb.x & 0xffff0000u)
            + asf(pa.y << 16) * asf(pb.y << 16) + asf(pa.y & 0xffff0000u) * asf(pb.y & 0xffff0000u)
            + asf(pa.z << 16) * asf(pb.z << 16) + asf(pa.z & 0xffff0000u) * asf(pb.z & 0xffff0000u)
            + asf(pa.w << 16) * asf(pb.w << 16) + asf(pa.w & 0xffff0000u) * asf(pb.w & 0xffff0000u);
#pragma unroll
    for (int off = 1; off < 8; off <<= 1) s += __shfl_xor(s, off);
    if (q == 0) {
        if (f32m) ((float*)out)[e] = s;
        else      ((unsigned short*)out)[e] = f2bf(s);
    }
}

extern "C" void kernel_launch(void* const* d_in, const int* in_sizes, int n_in,
                              void* d_out, int out_size, void* d_ws, size_t ws_size,
                              hipStream_t stream) {
    const void* x   = d_in[0];
    const int*  ei  = (const int*)d_in[1];
    const int*  eli = (const int*)d_in[2];
    const void* W1l = d_in[3];
    const void* b1  = d_in[4];
    const void* W1r = d_in[5];
    const void* W2l = d_in[6];
    const void* b2  = d_in[7];
    const void* W2r = d_in[8];

    char* ws = (char*)d_ws;
    const size_t offCnt  = 1024;                       // int[100000] -> 400 KB
    const size_t offWts  = 801024;                     // bf16[NWTS]  -> ~96 KB
    const size_t offCsr  = 1u << 20;                              // int[N*32]       12.8 MB
    const size_t offXb   = offCsr + (size_t)N_NODES * CAP * 4;    // xb  bf16[N,128] 25.6 MB
    const size_t offTbl  = offXb  + (size_t)N_NODES * 128 * 2;    // tbl bf16[N,64]  12.8 MB
    const size_t offTbr  = offTbl + (size_t)N_NODES * 64 * 2;     // tbr bf16[N,64]  12.8 MB
    const size_t offZb   = offTbr + (size_t)N_NODES * 64 * 2;     // zb  bf16[N,64]  12.8 MB
    // total = 1 MB + 12.8 + 25.6 + 12.8 + 12.8 + 12.8 = 77.8 MB (proven footprint)

    int*            cnt   = (int*)(ws + offCnt);
    unsigned short* wts   = (unsigned short*)(ws + offWts);
    int*            csr   = (int*)(ws + offCsr);
    unsigned short* xb    = (unsigned short*)(ws + offXb);
    unsigned short* tbl   = (unsigned short*)(ws + offTbl);
    unsigned short* tbr   = (unsigned short*)(ws + offTbr);
    unsigned short* zb    = (unsigned short*)(ws + offZb);

    // prep: cnt zero | weights->bf16 | x->bf16 (one streaming dispatch, self-detecting)
    k_prep<<<NB_C + NB_W + NB_X, 256, 0, stream>>>(W1l, b1, W1r, W2l, b2, W2r,
                                                   wts, x, xb, ei, cnt);

    k_fill<<<(N_EDGES + 255) / 256, 256, 0, stream>>>(ei, cnt, csr, x);

    // fused agg1+gemm1+gemm2: 32 nodes/block, 100000/32 = 3125 blocks exactly
    k_fused1<<<N_NODES / 32, 256, 0, stream>>>(cnt, csr, xb, wts, tbl, tbr);

    // agg2c: 4 nodes/wave -> 25000 waves -> 6250 blocks
    k_agg2c<<<6250, 256, 0, stream>>>(cnt, csr, tbl, tbr, wts, zb);

    // decode: 8 edges/wave -> 100000*8 threads -> 3125 blocks
    k_decode<<<(N_LABEL * 8) / 256, 256, 0, stream>>>(eli, zb, d_out, x, ei);
}